// Round 1
// baseline (890.872 us; speedup 1.0000x reference)
//
#include <hip/hip_runtime.h>
#include <math.h>

#define B_ 8
#define L_ 2048
#define D_ 512
#define LOG2L 11
#define TOPK 7

// ------------------------------------------------------------------
// GEMM: C[M,512] = A[M,512] @ W[512,512], fp32 row-major.
// 64x64 tile, 256 threads, each thread 4x4 outputs, BK=16.
// ------------------------------------------------------------------
#define BM 64
#define BN 64
#define BK 16

__global__ __launch_bounds__(256) void sgemm_kernel(
    const float* __restrict__ A, const float* __restrict__ W,
    float* __restrict__ C, int M)
{
  __shared__ float As[BK][BM];
  __shared__ float Ws[BK][BN];
  const int tid = threadIdx.x;
  const int tx = tid & 15, ty = tid >> 4;
  const int nb = D_ / BN;                 // 8 n-tiles
  const int m0 = (blockIdx.x / nb) * BM;
  const int n0 = (blockIdx.x % nb) * BN;

  float acc[4][4] = {};

  const int ar = tid >> 2;                // 0..63 (row in A tile)
  const int ac = (tid & 3) << 2;          // 0,4,8,12 (k in A tile)
  const int wr = tid >> 4;                // 0..15 (k in W tile)
  const int wc = (tid & 15) << 2;         // 0..60 (col in W tile)

  for (int k0 = 0; k0 < D_; k0 += BK) {
    float4 av = *reinterpret_cast<const float4*>(&A[(size_t)(m0 + ar) * D_ + k0 + ac]);
    float4 wv = *reinterpret_cast<const float4*>(&W[(size_t)(k0 + wr) * D_ + n0 + wc]);
    As[ac + 0][ar] = av.x;
    As[ac + 1][ar] = av.y;
    As[ac + 2][ar] = av.z;
    As[ac + 3][ar] = av.w;
    *reinterpret_cast<float4*>(&Ws[wr][wc]) = wv;
    __syncthreads();
#pragma unroll
    for (int k = 0; k < BK; ++k) {
      float4 a = *reinterpret_cast<const float4*>(&As[k][ty << 2]);
      float4 w = *reinterpret_cast<const float4*>(&Ws[k][tx << 2]);
      float aa[4] = {a.x, a.y, a.z, a.w};
      float ww[4] = {w.x, w.y, w.z, w.w};
#pragma unroll
      for (int i = 0; i < 4; ++i)
#pragma unroll
        for (int j = 0; j < 4; ++j)
          acc[i][j] = fmaf(aa[i], ww[j], acc[i][j]);
    }
    __syncthreads();
  }
#pragma unroll
  for (int i = 0; i < 4; ++i) {
    float4 o = {acc[i][0], acc[i][1], acc[i][2], acc[i][3]};
    *reinterpret_cast<float4*>(&C[(size_t)(m0 + (ty << 2) + i) * D_ + n0 + (tx << 2)]) = o;
  }
}

// ------------------------------------------------------------------
// In-LDS radix-2 2048-pt FFT machinery (DIT, input must be bit-reversed).
// SIGN = -1 forward, +1 inverse (unscaled).
// ------------------------------------------------------------------
__device__ __forceinline__ int bitrev11(int x) {
  return (int)(__brev((unsigned)x) >> (32 - LOG2L));
}

template <int SIGN>
__device__ __forceinline__ void fft2048_lds(float* re, float* im) {
  for (int s = 1; s <= LOG2L; ++s) {
    const int half = 1 << (s - 1);
    for (int j = (int)threadIdx.x; j < (L_ >> 1); j += 256) {
      const int pos = j & (half - 1);
      const int i0 = ((j >> (s - 1)) << s) + pos;
      const int i1 = i0 + half;
      const float ang = (float)SIGN * 6.283185307179586f * (float)pos / (float)(half << 1);
      float wi, wr;
      __sincosf(ang, &wi, &wr);
      const float br = re[i1], bi = im[i1];
      const float tr = br * wr - bi * wi;
      const float ti = br * wi + bi * wr;
      const float ar = re[i0], ai = im[i0];
      re[i0] = ar + tr; im[i0] = ai + ti;
      re[i1] = ar - tr; im[i1] = ai - ti;
    }
    __syncthreads();
  }
}

// ------------------------------------------------------------------
// Per (b,d): z = q[b,:,d] + i*k[b,:,d]; Z=FFT(z); split into Qf,Kf via
// Hermitian symmetry; P[f]=Qf*conj(Kf); atomicAdd into S[b][f] (f=0..1024).
// ------------------------------------------------------------------
__global__ __launch_bounds__(256) void corr_fft_kernel(
    const float* __restrict__ q, const float* __restrict__ k,
    float* __restrict__ S)
{
  __shared__ float re[L_];
  __shared__ float im[L_];
  const int wg = blockIdx.x;
  const int b = wg >> 9;          // / 512
  const int d = wg & (D_ - 1);
  const float* qb = q + (size_t)b * L_ * D_ + d;
  const float* kb = k + (size_t)b * L_ * D_ + d;
  for (int t = (int)threadIdx.x; t < L_; t += 256) {
    const int r = bitrev11(t);
    re[r] = qb[(size_t)t * D_];
    im[r] = kb[(size_t)t * D_];
  }
  __syncthreads();
  fft2048_lds<-1>(re, im);

  for (int f = (int)threadIdx.x; f <= (L_ / 2); f += 256) {
    const int fm = (L_ - f) & (L_ - 1);
    const float Ar = re[f],  Ai = im[f];
    const float Br = re[fm], Bi = -im[fm];      // conj(Z[L-f])
    const float Qr = 0.5f * (Ar + Br), Qi = 0.5f * (Ai + Bi);   // Qf
    const float Cr = 0.5f * (Ai - Bi), Ci = 0.5f * (Ar - Br);   // conj(Kf)
    const float Pr = Qr * Cr - Qi * Ci;
    const float Pi = Qr * Ci + Qi * Cr;
    atomicAdd(&S[((size_t)b * (L_ / 2 + 1) + f) * 2 + 0], Pr);
    atomicAdd(&S[((size_t)b * (L_ / 2 + 1) + f) * 2 + 1], Pi);
  }
}

// ------------------------------------------------------------------
// Per b: rebuild full Hermitian spectrum from S, inverse FFT, take Re,
// scale by 1/(512*2048) -> mean_value[b][l].
// ------------------------------------------------------------------
__global__ __launch_bounds__(256) void ifft_kernel(
    const float* __restrict__ S, float* __restrict__ mv)
{
  __shared__ float re[L_];
  __shared__ float im[L_];
  const int b = blockIdx.x;
  for (int f = (int)threadIdx.x; f < L_; f += 256) {
    const int fs = (f <= L_ / 2) ? f : (L_ - f);
    float sr = S[((size_t)b * (L_ / 2 + 1) + fs) * 2 + 0];
    float si = S[((size_t)b * (L_ / 2 + 1) + fs) * 2 + 1];
    if (f > L_ / 2) si = -si;
    const int r = bitrev11(f);
    re[r] = sr; im[r] = si;
  }
  __syncthreads();
  fft2048_lds<1>(re, im);
  const float scale = 1.0f / ((float)D_ * (float)L_);
  for (int l = (int)threadIdx.x; l < L_; l += 256)
    mv[(size_t)b * L_ + l] = re[l] * scale;
}

// ------------------------------------------------------------------
// Top-7 lags of sum_b mean_value (== argsort of mean over b), then
// per-batch softmax over the selected correlations.
// ------------------------------------------------------------------
__global__ __launch_bounds__(256) void topk_kernel(
    const float* __restrict__ mv, int* __restrict__ idx, float* __restrict__ wts)
{
  __shared__ float vals[L_];
  __shared__ float rv[256];
  __shared__ int ri[256];
  __shared__ int chosen[TOPK];
  const int tid = (int)threadIdx.x;
  for (int l = tid; l < L_; l += 256) {
    float s = 0.f;
    for (int b = 0; b < B_; ++b) s += mv[(size_t)b * L_ + l];
    vals[l] = s;
  }
  __syncthreads();
  for (int kk = 0; kk < TOPK; ++kk) {
    float best = -1e30f; int bi = L_;
    for (int l = tid; l < L_; l += 256)
      if (vals[l] > best) { best = vals[l]; bi = l; }
    rv[tid] = best; ri[tid] = bi;
    __syncthreads();
    if (tid == 0) {
      float m = -1e30f; int mi = L_;
      for (int i = 0; i < 256; ++i)
        if (rv[i] > m || (rv[i] == m && ri[i] < mi)) { m = rv[i]; mi = ri[i]; }
      chosen[kk] = mi;
      idx[kk] = mi;
      vals[mi] = -1e30f;
    }
    __syncthreads();
  }
  if (tid < B_) {
    float w[TOPK];
    float mx = -1e30f;
    for (int kk = 0; kk < TOPK; ++kk) {
      w[kk] = mv[(size_t)tid * L_ + chosen[kk]];
      mx = fmaxf(mx, w[kk]);
    }
    float sum = 0.f;
    for (int kk = 0; kk < TOPK; ++kk) { w[kk] = __expf(w[kk] - mx); sum += w[kk]; }
    const float inv = 1.0f / sum;
    for (int kk = 0; kk < TOPK; ++kk) wts[tid * TOPK + kk] = w[kk] * inv;
  }
}

// ------------------------------------------------------------------
// context[b,l,:] = sum_k wts[b,k] * v[b,(l+idx[k])%L,:]
// one block per (b,l); 128 threads x float4 = 512 channels
// ------------------------------------------------------------------
__global__ __launch_bounds__(128) void context_kernel(
    const float* __restrict__ v, const int* __restrict__ idx,
    const float* __restrict__ wts, float* __restrict__ ctx)
{
  const int bl = (int)blockIdx.x;
  const int b = bl >> LOG2L;
  const int l = bl & (L_ - 1);
  const int c = (int)threadIdx.x;     // float4 lane
  float4 acc = {0.f, 0.f, 0.f, 0.f};
#pragma unroll
  for (int kk = 0; kk < TOPK; ++kk) {
    const float w = wts[b * TOPK + kk];
    const int src = (l + idx[kk]) & (L_ - 1);
    const float4 x = reinterpret_cast<const float4*>(v + ((size_t)b * L_ + src) * D_)[c];
    acc.x = fmaf(w, x.x, acc.x);
    acc.y = fmaf(w, x.y, acc.y);
    acc.z = fmaf(w, x.z, acc.z);
    acc.w = fmaf(w, x.w, acc.w);
  }
  reinterpret_cast<float4*>(ctx + ((size_t)b * L_ + l) * D_)[c] = acc;
}

// ------------------------------------------------------------------
extern "C" void kernel_launch(void* const* d_in, const int* in_sizes, int n_in,
                              void* d_out, int out_size, void* d_ws, size_t ws_size,
                              hipStream_t stream)
{
  (void)in_sizes; (void)n_in; (void)out_size; (void)ws_size;
  const float* Q   = (const float*)d_in[0];
  const float* K   = (const float*)d_in[1];
  const float* V   = (const float*)d_in[2];
  const float* WQ  = (const float*)d_in[3];
  const float* WK  = (const float*)d_in[4];
  const float* WV  = (const float*)d_in[5];
  const float* Wfc = (const float*)d_in[6];
  float* out = (float*)d_out;

  char* ws = (char*)d_ws;
  const size_t sz_mat = (size_t)B_ * L_ * D_ * sizeof(float);   // 33.55 MB
  float* buf0 = (float*)(ws);                                    // q_s, later v_s
  float* buf1 = (float*)(ws + sz_mat);                           // k_s, later context
  float* S    = (float*)(ws + 2 * sz_mat);                       // 8 x 1025 x 2 fp32
  float* mv   = (float*)(ws + 2 * sz_mat + (size_t)B_ * (L_/2+1) * 2 * sizeof(float));
  int*   idx  = (int*)((char*)mv + (size_t)B_ * L_ * sizeof(float));
  float* wts  = (float*)((char*)idx + 64);

  const int M = B_ * L_;
  const int gemm_grid = (M / BM) * (D_ / BN);

  sgemm_kernel<<<gemm_grid, 256, 0, stream>>>(Q, WQ, buf0, M);   // q_s
  sgemm_kernel<<<gemm_grid, 256, 0, stream>>>(K, WK, buf1, M);   // k_s
  hipMemsetAsync(S, 0, (size_t)B_ * (L_/2+1) * 2 * sizeof(float), stream);
  corr_fft_kernel<<<B_ * D_, 256, 0, stream>>>(buf0, buf1, S);
  ifft_kernel<<<B_, 256, 0, stream>>>(S, mv);
  topk_kernel<<<1, 256, 0, stream>>>(mv, idx, wts);
  sgemm_kernel<<<gemm_grid, 256, 0, stream>>>(V, WV, buf0, M);   // v_s (reuse)
  context_kernel<<<B_ * L_, 128, 0, stream>>>(buf0, idx, wts, buf1);
  sgemm_kernel<<<gemm_grid, 256, 0, stream>>>(buf1, Wfc, out, M);
}

// Round 2
// 724.470 us; speedup vs baseline: 1.2297x; 1.2297x over previous
//
#include <hip/hip_runtime.h>
#include <math.h>

#define B_ 8
#define L_ 2048
#define D_ 512
#define LOG2L 11
#define TOPK 7
#define M_ (B_ * L_)     // 16384

// ------------------------------------------------------------------
// GEMM: C = A[M,512] @ W[512,512], fp32 row-major.
// TR=0: C[m][n] (row-major [M,512]).  TR=1: C[n][m] (row-major [512,M]).
// 64x64 tile, 256 threads, each thread 4x4 outputs, BK=16.
// ------------------------------------------------------------------
#define BM 64
#define BN 64
#define BK 16

template <int TR>
__global__ __launch_bounds__(256) void sgemm_kernel(
    const float* __restrict__ A, const float* __restrict__ W,
    float* __restrict__ C, int M)
{
  __shared__ float As[BK][BM];
  __shared__ float Ws[BK][BN];
  const int tid = threadIdx.x;
  const int tx = tid & 15, ty = tid >> 4;
  const int nb = D_ / BN;                 // 8 n-tiles
  const int m0 = (blockIdx.x / nb) * BM;
  const int n0 = (blockIdx.x % nb) * BN;

  float acc[4][4] = {};

  const int ar = tid >> 2;                // 0..63 (row in A tile)
  const int ac = (tid & 3) << 2;          // 0,4,8,12 (k in A tile)
  const int wr = tid >> 4;                // 0..15 (k in W tile)
  const int wc = (tid & 15) << 2;         // 0..60 (col in W tile)

  for (int k0 = 0; k0 < D_; k0 += BK) {
    float4 av = *reinterpret_cast<const float4*>(&A[(size_t)(m0 + ar) * D_ + k0 + ac]);
    float4 wv = *reinterpret_cast<const float4*>(&W[(size_t)(k0 + wr) * D_ + n0 + wc]);
    As[ac + 0][ar] = av.x;
    As[ac + 1][ar] = av.y;
    As[ac + 2][ar] = av.z;
    As[ac + 3][ar] = av.w;
    *reinterpret_cast<float4*>(&Ws[wr][wc]) = wv;
    __syncthreads();
#pragma unroll
    for (int k = 0; k < BK; ++k) {
      float4 a = *reinterpret_cast<const float4*>(&As[k][ty << 2]);
      float4 w = *reinterpret_cast<const float4*>(&Ws[k][tx << 2]);
      float aa[4] = {a.x, a.y, a.z, a.w};
      float ww[4] = {w.x, w.y, w.z, w.w};
#pragma unroll
      for (int i = 0; i < 4; ++i)
#pragma unroll
        for (int j = 0; j < 4; ++j)
          acc[i][j] = fmaf(aa[i], ww[j], acc[i][j]);
    }
    __syncthreads();
  }
  if (TR == 0) {
#pragma unroll
    for (int i = 0; i < 4; ++i) {
      float4 o = {acc[i][0], acc[i][1], acc[i][2], acc[i][3]};
      *reinterpret_cast<float4*>(&C[(size_t)(m0 + (ty << 2) + i) * D_ + n0 + (tx << 2)]) = o;
    }
  } else {
#pragma unroll
    for (int j = 0; j < 4; ++j) {
      float4 o = {acc[0][j], acc[1][j], acc[2][j], acc[3][j]};
      *reinterpret_cast<float4*>(&C[(size_t)(n0 + (tx << 2) + j) * M + m0 + (ty << 2)]) = o;
    }
  }
}

__device__ __forceinline__ int rev11(int x) {
  return (int)(__brev((unsigned)x) >> (32 - LOG2L));
}

// ------------------------------------------------------------------
// corr_fft v2: one block per (b, 4 d-columns). Input qT/kT in [d][b*L+l]
// layout (contiguous rows). Forward DIF (natural in -> bitrev out) with
// LDS twiddle tables; Hermitian split in position space; P accumulated
// in registers over 4 columns; atomicAdd into S[b][p] (bitrev order).
// ------------------------------------------------------------------
#define DCHUNK 4

__global__ __launch_bounds__(256) void corr_fft_kernel(
    const float* __restrict__ qT, const float* __restrict__ kT,
    float* __restrict__ S)
{
  __shared__ float re[L_];
  __shared__ float im[L_];
  __shared__ float twr[L_];   // entry half+pos = exp(-i*pi*pos/half)
  __shared__ float twi[L_];
  const int tid = (int)threadIdx.x;
  const int blk = (int)blockIdx.x;
  const int b = blk >> 7;                    // 128 chunks per batch
  const int d0 = (blk & 127) * DCHUNK;

  // twiddle tables (per-stage contiguous)
  for (int t = tid; t < L_; t += 256) {
    if (t == 0) { twr[0] = 1.f; twi[0] = 0.f; continue; }
    const int h = 31 - __clz((unsigned)t);
    const int half = 1 << h;
    const int pos = t - half;
    const float ang = -3.14159265358979323846f * (float)pos / (float)half;
    float si, co;
    __sincosf(ang, &si, &co);
    twr[t] = co; twi[t] = si;
  }

  float pr[8] = {}, pi_[8] = {};

  for (int dc = 0; dc < DCHUNK; ++dc) {
    const int d = d0 + dc;
    const float* qrow = qT + (size_t)d * M_ + (size_t)b * L_;
    const float* krow = kT + (size_t)d * M_ + (size_t)b * L_;
    __syncthreads();    // prev pairing reads / twiddle fill done before overwrite
    for (int t = tid * 4; t < L_; t += 1024) {
      float4 qv = *reinterpret_cast<const float4*>(qrow + t);
      float4 kv = *reinterpret_cast<const float4*>(krow + t);
      re[t + 0] = qv.x; re[t + 1] = qv.y; re[t + 2] = qv.z; re[t + 3] = qv.w;
      im[t + 0] = kv.x; im[t + 1] = kv.y; im[t + 2] = kv.z; im[t + 3] = kv.w;
    }
    __syncthreads();

    // forward DIF: natural in, bit-reversed out
    for (int s = LOG2L; s >= 1; --s) {
      const int half = 1 << (s - 1);
      for (int j = tid; j < (L_ >> 1); j += 256) {
        const int pos = j & (half - 1);
        const int i0 = ((j >> (s - 1)) << s) + pos;
        const int i1 = i0 + half;
        const float ar = re[i0], ai = im[i0];
        const float br = re[i1], bi = im[i1];
        re[i0] = ar + br; im[i0] = ai + bi;
        const float tr = ar - br, ti = ai - bi;
        const float wr = twr[half + pos], wi = twi[half + pos];
        re[i1] = tr * wr - ti * wi;
        im[i1] = tr * wi + ti * wr;
      }
      __syncthreads();
    }

    // Hermitian split + product, position space (p holds freq rev(p))
#pragma unroll
    for (int i = 0; i < 8; ++i) {
      const int p = tid + 256 * i;
      const int f = rev11(p);
      const int fm = (L_ - f) & (L_ - 1);
      const int pm = rev11(fm);
      const float Ar = re[p],  Ai = im[p];
      const float Br = re[pm], Bi = -im[pm];     // conj(Z[L-f])
      const float Qr = 0.5f * (Ar + Br), Qi = 0.5f * (Ai + Bi);
      const float Cr = 0.5f * (Ai - Bi), Ci = 0.5f * (Ar - Br);
      pr[i]  += Qr * Cr - Qi * Ci;
      pi_[i] += Qr * Ci + Qi * Cr;
    }
  }

#pragma unroll
  for (int i = 0; i < 8; ++i) {
    const int p = tid + 256 * i;
    atomicAdd(&S[((size_t)b * L_ + p) * 2 + 0], pr[i]);
    atomicAdd(&S[((size_t)b * L_ + p) * 2 + 1], pi_[i]);
  }
}

// ------------------------------------------------------------------
// Inverse DIT (bit-rev in, natural out), per b. S is full spectrum in
// bit-reversed order -> load directly, no reconstruction.
// ------------------------------------------------------------------
__global__ __launch_bounds__(256) void ifft_kernel(
    const float* __restrict__ S, float* __restrict__ mv)
{
  __shared__ float re[L_];
  __shared__ float im[L_];
  const int b = blockIdx.x;
  for (int p = (int)threadIdx.x; p < L_; p += 256) {
    re[p] = S[((size_t)b * L_ + p) * 2 + 0];
    im[p] = S[((size_t)b * L_ + p) * 2 + 1];
  }
  __syncthreads();
  for (int s = 1; s <= LOG2L; ++s) {
    const int half = 1 << (s - 1);
    for (int j = (int)threadIdx.x; j < (L_ >> 1); j += 256) {
      const int pos = j & (half - 1);
      const int i0 = ((j >> (s - 1)) << s) + pos;
      const int i1 = i0 + half;
      const float ang = 3.14159265358979323846f * (float)pos / (float)half;
      float wi, wr;
      __sincosf(ang, &wi, &wr);
      const float br = re[i1], bi = im[i1];
      const float tr = br * wr - bi * wi;
      const float ti = br * wi + bi * wr;
      const float ar = re[i0], ai = im[i0];
      re[i0] = ar + tr; im[i0] = ai + ti;
      re[i1] = ar - tr; im[i1] = ai - ti;
    }
    __syncthreads();
  }
  const float scale = 1.0f / ((float)D_ * (float)L_);
  for (int l = (int)threadIdx.x; l < L_; l += 256)
    mv[(size_t)b * L_ + l] = re[l] * scale;
}

// ------------------------------------------------------------------
// Top-7 lags of sum_b mean_value, then per-batch softmax.
// ------------------------------------------------------------------
__global__ __launch_bounds__(256) void topk_kernel(
    const float* __restrict__ mv, int* __restrict__ idx, float* __restrict__ wts)
{
  __shared__ float vals[L_];
  __shared__ float rv[256];
  __shared__ int ri[256];
  __shared__ int chosen[TOPK];
  const int tid = (int)threadIdx.x;
  for (int l = tid; l < L_; l += 256) {
    float s = 0.f;
    for (int b = 0; b < B_; ++b) s += mv[(size_t)b * L_ + l];
    vals[l] = s;
  }
  __syncthreads();
  for (int kk = 0; kk < TOPK; ++kk) {
    float best = -1e30f; int bi = L_;
    for (int l = tid; l < L_; l += 256)
      if (vals[l] > best) { best = vals[l]; bi = l; }
    rv[tid] = best; ri[tid] = bi;
    __syncthreads();
    if (tid == 0) {
      float m = -1e30f; int mi = L_;
      for (int i = 0; i < 256; ++i)
        if (rv[i] > m || (rv[i] == m && ri[i] < mi)) { m = rv[i]; mi = ri[i]; }
      chosen[kk] = mi;
      idx[kk] = mi;
      vals[mi] = -1e30f;
    }
    __syncthreads();
  }
  if (tid < B_) {
    float w[TOPK];
    float mx = -1e30f;
    for (int kk = 0; kk < TOPK; ++kk) {
      w[kk] = mv[(size_t)tid * L_ + chosen[kk]];
      mx = fmaxf(mx, w[kk]);
    }
    float sum = 0.f;
    for (int kk = 0; kk < TOPK; ++kk) { w[kk] = __expf(w[kk] - mx); sum += w[kk]; }
    const float inv = 1.0f / sum;
    for (int kk = 0; kk < TOPK; ++kk) wts[tid * TOPK + kk] = w[kk] * inv;
  }
}

// ------------------------------------------------------------------
// context[b,l,:] = sum_k wts[b,k] * v[b,(l+idx[k])%L,:]
// ------------------------------------------------------------------
__global__ __launch_bounds__(128) void context_kernel(
    const float* __restrict__ v, const int* __restrict__ idx,
    const float* __restrict__ wts, float* __restrict__ ctx)
{
  const int bl = (int)blockIdx.x;
  const int b = bl >> LOG2L;
  const int l = bl & (L_ - 1);
  const int c = (int)threadIdx.x;
  float4 acc = {0.f, 0.f, 0.f, 0.f};
#pragma unroll
  for (int kk = 0; kk < TOPK; ++kk) {
    const float w = wts[b * TOPK + kk];
    const int src = (l + idx[kk]) & (L_ - 1);
    const float4 x = reinterpret_cast<const float4*>(v + ((size_t)b * L_ + src) * D_)[c];
    acc.x = fmaf(w, x.x, acc.x);
    acc.y = fmaf(w, x.y, acc.y);
    acc.z = fmaf(w, x.z, acc.z);
    acc.w = fmaf(w, x.w, acc.w);
  }
  reinterpret_cast<float4*>(ctx + ((size_t)b * L_ + l) * D_)[c] = acc;
}

// ------------------------------------------------------------------
extern "C" void kernel_launch(void* const* d_in, const int* in_sizes, int n_in,
                              void* d_out, int out_size, void* d_ws, size_t ws_size,
                              hipStream_t stream)
{
  (void)in_sizes; (void)n_in; (void)out_size; (void)ws_size;
  const float* Q   = (const float*)d_in[0];
  const float* K   = (const float*)d_in[1];
  const float* V   = (const float*)d_in[2];
  const float* WQ  = (const float*)d_in[3];
  const float* WK  = (const float*)d_in[4];
  const float* WV  = (const float*)d_in[5];
  const float* Wfc = (const float*)d_in[6];
  float* out = (float*)d_out;

  char* ws = (char*)d_ws;
  const size_t sz_mat = (size_t)M_ * D_ * sizeof(float);         // 33.55 MB
  float* buf0 = (float*)(ws);                                    // qT, later v_s
  float* buf1 = (float*)(ws + sz_mat);                           // kT, later context
  float* S    = (float*)(ws + 2 * sz_mat);                       // 8 x 2048 x 2 fp32
  float* mv   = (float*)((char*)S + (size_t)B_ * L_ * 2 * sizeof(float));
  int*   idx  = (int*)((char*)mv + (size_t)B_ * L_ * sizeof(float));
  float* wts  = (float*)((char*)idx + 64);

  const int gemm_grid = (M_ / BM) * (D_ / BN);

  sgemm_kernel<1><<<gemm_grid, 256, 0, stream>>>(Q, WQ, buf0, M_);   // qT [d][b*L+l]
  sgemm_kernel<1><<<gemm_grid, 256, 0, stream>>>(K, WK, buf1, M_);   // kT
  hipMemsetAsync(S, 0, (size_t)B_ * L_ * 2 * sizeof(float), stream);
  corr_fft_kernel<<<B_ * (D_ / DCHUNK), 256, 0, stream>>>(buf0, buf1, S);
  ifft_kernel<<<B_, 256, 0, stream>>>(S, mv);
  topk_kernel<<<1, 256, 0, stream>>>(mv, idx, wts);
  sgemm_kernel<0><<<gemm_grid, 256, 0, stream>>>(V, WV, buf0, M_);   // v_s
  context_kernel<<<B_ * L_, 128, 0, stream>>>(buf0, idx, wts, buf1);
  sgemm_kernel<0><<<gemm_grid, 256, 0, stream>>>(buf1, Wfc, out, M_);
}

// Round 3
// 414.275 us; speedup vs baseline: 2.1504x; 1.7488x over previous
//
#include <hip/hip_runtime.h>
#include <math.h>

#define B_ 8
#define L_ 2048
#define D_ 512
#define LOG2L 11
#define TOPK 7
#define M_ (B_ * L_)     // 16384

typedef __attribute__((ext_vector_type(8))) _Float16 half8;
typedef __attribute__((ext_vector_type(4))) _Float16 half4;
typedef __attribute__((ext_vector_type(4))) float f32x4;

// ------------------------------------------------------------------
// convw: W fp32 [512][512] row-major (k-major) -> Wt f16 [512][512]
// with Wt[n][k] = W[k][n]. 64x64 tiles via LDS.
// ------------------------------------------------------------------
__global__ __launch_bounds__(256) void convw_kernel(
    const float* __restrict__ W, _Float16* __restrict__ Wt)
{
  __shared__ float tile[64][65];
  const int t = (int)threadIdx.x;
  const int k0 = ((int)blockIdx.x >> 3) * 64;
  const int n0 = ((int)blockIdx.x & 7) * 64;
#pragma unroll
  for (int i = 0; i < 4; ++i) {
    const int kl = (t >> 4) + i * 16;
    const float4 v = *reinterpret_cast<const float4*>(&W[(size_t)(k0 + kl) * D_ + n0 + (t & 15) * 4]);
    tile[kl][(t & 15) * 4 + 0] = v.x;
    tile[kl][(t & 15) * 4 + 1] = v.y;
    tile[kl][(t & 15) * 4 + 2] = v.z;
    tile[kl][(t & 15) * 4 + 3] = v.w;
  }
  __syncthreads();
  const int nl = t >> 2, q = t & 3;
  half8 h0, h1;
#pragma unroll
  for (int j = 0; j < 8; ++j) {
    h0[j] = (_Float16)tile[q * 16 + j][nl];
    h1[j] = (_Float16)tile[q * 16 + 8 + j][nl];
  }
  _Float16* dst = &Wt[(size_t)(n0 + nl) * D_ + k0 + q * 16];
  *reinterpret_cast<half8*>(dst) = h0;
  *reinterpret_cast<half8*>(dst + 8) = h1;
}

// ------------------------------------------------------------------
// MFMA f16 GEMM: C = A[M,512] @ W[512,512] using Wt[n][k] f16.
// 128x128 tile, BK=32, 256 thr = 4 waves (2x2), wave tile 64x64 (4x4
// frags of 16x16x32). LDS rows padded to 40 halfs (80 B) -> 2-way-free
// ds_read_b128. INBF: 0 = A fp32 (convert in staging), 1 = A f16.
// OUTMODE: 0 = fp32 [M,512]; 1 = fp32 transposed [512][M]; 2 = f16 [M,512].
// ------------------------------------------------------------------
#define LDSTR 40

template <int INBF, int OUTMODE>
__global__ __launch_bounds__(256) void gemm_f16_kernel(
    const float* __restrict__ Af, const _Float16* __restrict__ Ah,
    const _Float16* __restrict__ Wt,
    float* __restrict__ Cf, _Float16* __restrict__ Ch)
{
  __shared__ __align__(16) char smem[128 * LDSTR * 2 * 2];   // 20480 B
  _Float16* sA = (_Float16*)smem;
  _Float16* sB = sA + 128 * LDSTR;

  const int tid = (int)threadIdx.x;
  const int lane = tid & 63, wave = tid >> 6;
  const int wr = (wave >> 1) << 6, wc = (wave & 1) << 6;
  const int m0 = ((int)blockIdx.x >> 2) << 7;
  const int n0 = ((int)blockIdx.x & 3) << 7;

  const int srow = tid >> 1;            // 0..127
  const int sc0 = (tid & 1) << 4;       // 0 / 16

  f32x4 acc[4][4];
  const f32x4 zero = {0.f, 0.f, 0.f, 0.f};
#pragma unroll
  for (int i = 0; i < 4; ++i)
#pragma unroll
    for (int j = 0; j < 4; ++j) acc[i][j] = zero;

  const int fr = lane & 15;
  const int g8 = (lane >> 4) << 3;

  for (int k0 = 0; k0 < D_; k0 += 32) {
    half8 ha0, ha1, hb0, hb1;
    if constexpr (INBF == 0) {
      const float* ap = Af + (size_t)(m0 + srow) * D_ + k0 + sc0;
      float tmp[16];
#pragma unroll
      for (int j = 0; j < 4; ++j) {
        const float4 v = *reinterpret_cast<const float4*>(ap + j * 4);
        tmp[j * 4 + 0] = v.x; tmp[j * 4 + 1] = v.y;
        tmp[j * 4 + 2] = v.z; tmp[j * 4 + 3] = v.w;
      }
#pragma unroll
      for (int j = 0; j < 8; ++j) { ha0[j] = (_Float16)tmp[j]; ha1[j] = (_Float16)tmp[8 + j]; }
    } else {
      const _Float16* ap = Ah + (size_t)(m0 + srow) * D_ + k0 + sc0;
      ha0 = *reinterpret_cast<const half8*>(ap);
      ha1 = *reinterpret_cast<const half8*>(ap + 8);
    }
    {
      const _Float16* bp = Wt + (size_t)(n0 + srow) * D_ + k0 + sc0;
      hb0 = *reinterpret_cast<const half8*>(bp);
      hb1 = *reinterpret_cast<const half8*>(bp + 8);
    }

    __syncthreads();    // previous iteration's fragment reads done
    *reinterpret_cast<half8*>(&sA[srow * LDSTR + sc0]) = ha0;
    *reinterpret_cast<half8*>(&sA[srow * LDSTR + sc0 + 8]) = ha1;
    *reinterpret_cast<half8*>(&sB[srow * LDSTR + sc0]) = hb0;
    *reinterpret_cast<half8*>(&sB[srow * LDSTR + sc0 + 8]) = hb1;
    __syncthreads();

    half8 afr[4], bfr[4];
#pragma unroll
    for (int i = 0; i < 4; ++i) {
      afr[i] = *reinterpret_cast<const half8*>(&sA[(wr + i * 16 + fr) * LDSTR + g8]);
      bfr[i] = *reinterpret_cast<const half8*>(&sB[(wc + i * 16 + fr) * LDSTR + g8]);
    }
#pragma unroll
    for (int mi = 0; mi < 4; ++mi)
#pragma unroll
      for (int ni = 0; ni < 4; ++ni)
        acc[mi][ni] = __builtin_amdgcn_mfma_f32_16x16x32_f16(afr[mi], bfr[ni], acc[mi][ni], 0, 0, 0);
  }

  const int orow = (lane >> 4) << 2;
  const int ocol = lane & 15;
  if constexpr (OUTMODE == 0) {
#pragma unroll
    for (int mi = 0; mi < 4; ++mi)
#pragma unroll
      for (int ni = 0; ni < 4; ++ni)
#pragma unroll
        for (int r = 0; r < 4; ++r)
          Cf[(size_t)(m0 + wr + mi * 16 + orow + r) * D_ + n0 + wc + ni * 16 + ocol] = acc[mi][ni][r];
  } else if constexpr (OUTMODE == 2) {
#pragma unroll
    for (int mi = 0; mi < 4; ++mi)
#pragma unroll
      for (int ni = 0; ni < 4; ++ni)
#pragma unroll
        for (int r = 0; r < 4; ++r)
          Ch[(size_t)(m0 + wr + mi * 16 + orow + r) * D_ + n0 + wc + ni * 16 + ocol] = (_Float16)acc[mi][ni][r];
  } else {
    // transposed fp32 output via per-wave LDS transpose (reuses tile LDS)
    float* tb = (float*)smem + wave * (64 * 17);
#pragma unroll 1
    for (int ni = 0; ni < 4; ++ni) {
      __syncthreads();
#pragma unroll
      for (int mi = 0; mi < 4; ++mi)
#pragma unroll
        for (int r = 0; r < 4; ++r)
          tb[(mi * 16 + orow + r) * 17 + ocol] = acc[mi][ni][r];
      __syncthreads();
      const int nl = lane >> 2, q = lane & 3;
      const size_t nrow = (size_t)(n0 + wc + ni * 16 + nl) * M_ + m0 + wr;
#pragma unroll
      for (int c = 0; c < 4; ++c) {
        const int mb = q * 16 + c * 4;
        const float4 vv = {tb[(mb + 0) * 17 + nl], tb[(mb + 1) * 17 + nl],
                           tb[(mb + 2) * 17 + nl], tb[(mb + 3) * 17 + nl]};
        *reinterpret_cast<float4*>(&Cf[nrow + mb]) = vv;
      }
    }
  }
}

// ------------------------------------------------------------------
// In-LDS radix-2 2048-pt FFT pieces (unchanged from R2 — verified).
// ------------------------------------------------------------------
__device__ __forceinline__ int rev11(int x) {
  return (int)(__brev((unsigned)x) >> (32 - LOG2L));
}

#define DCHUNK 4

__global__ __launch_bounds__(256) void corr_fft_kernel(
    const float* __restrict__ qT, const float* __restrict__ kT,
    float* __restrict__ S)
{
  __shared__ float re[L_];
  __shared__ float im[L_];
  __shared__ float twr[L_];
  __shared__ float twi[L_];
  const int tid = (int)threadIdx.x;
  const int blk = (int)blockIdx.x;
  const int b = blk >> 7;
  const int d0 = (blk & 127) * DCHUNK;

  for (int t = tid; t < L_; t += 256) {
    if (t == 0) { twr[0] = 1.f; twi[0] = 0.f; continue; }
    const int h = 31 - __clz((unsigned)t);
    const int half = 1 << h;
    const int pos = t - half;
    const float ang = -3.14159265358979323846f * (float)pos / (float)half;
    float si, co;
    __sincosf(ang, &si, &co);
    twr[t] = co; twi[t] = si;
  }

  float pr[8] = {}, pi_[8] = {};

  for (int dc = 0; dc < DCHUNK; ++dc) {
    const int d = d0 + dc;
    const float* qrow = qT + (size_t)d * M_ + (size_t)b * L_;
    const float* krow = kT + (size_t)d * M_ + (size_t)b * L_;
    __syncthreads();
    for (int t = tid * 4; t < L_; t += 1024) {
      float4 qv = *reinterpret_cast<const float4*>(qrow + t);
      float4 kv = *reinterpret_cast<const float4*>(krow + t);
      re[t + 0] = qv.x; re[t + 1] = qv.y; re[t + 2] = qv.z; re[t + 3] = qv.w;
      im[t + 0] = kv.x; im[t + 1] = kv.y; im[t + 2] = kv.z; im[t + 3] = kv.w;
    }
    __syncthreads();

    for (int s = LOG2L; s >= 1; --s) {
      const int half = 1 << (s - 1);
      for (int j = tid; j < (L_ >> 1); j += 256) {
        const int pos = j & (half - 1);
        const int i0 = ((j >> (s - 1)) << s) + pos;
        const int i1 = i0 + half;
        const float ar = re[i0], ai = im[i0];
        const float br = re[i1], bi = im[i1];
        re[i0] = ar + br; im[i0] = ai + bi;
        const float tr = ar - br, ti = ai - bi;
        const float wr = twr[half + pos], wi = twi[half + pos];
        re[i1] = tr * wr - ti * wi;
        im[i1] = tr * wi + ti * wr;
      }
      __syncthreads();
    }

#pragma unroll
    for (int i = 0; i < 8; ++i) {
      const int p = tid + 256 * i;
      const int f = rev11(p);
      const int fm = (L_ - f) & (L_ - 1);
      const int pm = rev11(fm);
      const float Ar = re[p],  Ai = im[p];
      const float Br = re[pm], Bi = -im[pm];
      const float Qr = 0.5f * (Ar + Br), Qi = 0.5f * (Ai + Bi);
      const float Cr = 0.5f * (Ai - Bi), Ci = 0.5f * (Ar - Br);
      pr[i]  += Qr * Cr - Qi * Ci;
      pi_[i] += Qr * Ci + Qi * Cr;
    }
  }

#pragma unroll
  for (int i = 0; i < 8; ++i) {
    const int p = tid + 256 * i;
    atomicAdd(&S[((size_t)b * L_ + p) * 2 + 0], pr[i]);
    atomicAdd(&S[((size_t)b * L_ + p) * 2 + 1], pi_[i]);
  }
}

__global__ __launch_bounds__(256) void ifft_kernel(
    const float* __restrict__ S, float* __restrict__ mv)
{
  __shared__ float re[L_];
  __shared__ float im[L_];
  const int b = blockIdx.x;
  for (int p = (int)threadIdx.x; p < L_; p += 256) {
    re[p] = S[((size_t)b * L_ + p) * 2 + 0];
    im[p] = S[((size_t)b * L_ + p) * 2 + 1];
  }
  __syncthreads();
  for (int s = 1; s <= LOG2L; ++s) {
    const int half = 1 << (s - 1);
    for (int j = (int)threadIdx.x; j < (L_ >> 1); j += 256) {
      const int pos = j & (half - 1);
      const int i0 = ((j >> (s - 1)) << s) + pos;
      const int i1 = i0 + half;
      const float ang = 3.14159265358979323846f * (float)pos / (float)half;
      float wi, wr;
      __sincosf(ang, &wi, &wr);
      const float br = re[i1], bi = im[i1];
      const float tr = br * wr - bi * wi;
      const float ti = br * wi + bi * wr;
      const float ar = re[i0], ai = im[i0];
      re[i0] = ar + tr; im[i0] = ai + ti;
      re[i1] = ar - tr; im[i1] = ai - ti;
    }
    __syncthreads();
  }
  const float scale = 1.0f / ((float)D_ * (float)L_);
  for (int l = (int)threadIdx.x; l < L_; l += 256)
    mv[(size_t)b * L_ + l] = re[l] * scale;
}

// ------------------------------------------------------------------
// topk v2: 1024 threads, shuffle-reduce argmax x7, then softmax.
// ------------------------------------------------------------------
__global__ __launch_bounds__(1024) void topk_kernel(
    const float* __restrict__ mv, int* __restrict__ idx, float* __restrict__ wts)
{
  __shared__ float vals[L_];
  __shared__ float wm[16];
  __shared__ int wi[16];
  __shared__ int chosen[TOPK];
  const int t = (int)threadIdx.x;
  const int lane = t & 63, wv = t >> 6;
  float s0 = 0.f, s1 = 0.f;
#pragma unroll
  for (int b = 0; b < B_; ++b) {
    s0 += mv[(size_t)b * L_ + t];
    s1 += mv[(size_t)b * L_ + t + 1024];
  }
  vals[t] = s0; vals[t + 1024] = s1;
  __syncthreads();
  for (int kk = 0; kk < TOPK; ++kk) {
    float v0 = vals[t]; int i0 = t;
    const float v1 = vals[t + 1024];
    if (v1 > v0) { v0 = v1; i0 = t + 1024; }
#pragma unroll
    for (int off = 32; off; off >>= 1) {
      const float ov = __shfl_xor(v0, off, 64);
      const int oi = __shfl_xor(i0, off, 64);
      if (ov > v0 || (ov == v0 && oi < i0)) { v0 = ov; i0 = oi; }
    }
    if (lane == 0) { wm[wv] = v0; wi[wv] = i0; }
    __syncthreads();
    if (t == 0) {
      float m = wm[0]; int mi = wi[0];
      for (int i2 = 1; i2 < 16; ++i2)
        if (wm[i2] > m || (wm[i2] == m && wi[i2] < mi)) { m = wm[i2]; mi = wi[i2]; }
      chosen[kk] = mi; idx[kk] = mi; vals[mi] = -1e30f;
    }
    __syncthreads();
  }
  if (t < B_) {
    float w[TOPK];
    float mx = -1e30f;
#pragma unroll
    for (int kk = 0; kk < TOPK; ++kk) {
      w[kk] = mv[(size_t)t * L_ + chosen[kk]];
      mx = fmaxf(mx, w[kk]);
    }
    float sum = 0.f;
#pragma unroll
    for (int kk = 0; kk < TOPK; ++kk) { w[kk] = __expf(w[kk] - mx); sum += w[kk]; }
    const float inv = 1.0f / sum;
#pragma unroll
    for (int kk = 0; kk < TOPK; ++kk) wts[t * TOPK + kk] = w[kk] * inv;
  }
}

// ------------------------------------------------------------------
// context: f16 in, f16 out. ctx[b,l,:] = sum_k w[b,k]*v[b,(l+idx[k])%L,:]
// ------------------------------------------------------------------
__global__ __launch_bounds__(128) void context_kernel(
    const _Float16* __restrict__ v, const int* __restrict__ idx,
    const float* __restrict__ wts, _Float16* __restrict__ ctx)
{
  const int bl = (int)blockIdx.x;
  const int b = bl >> LOG2L;
  const int l = bl & (L_ - 1);
  const int c = (int)threadIdx.x;     // half4 lane
  float acc0 = 0.f, acc1 = 0.f, acc2 = 0.f, acc3 = 0.f;
#pragma unroll
  for (int kk = 0; kk < TOPK; ++kk) {
    const float w = wts[b * TOPK + kk];
    const int src = (l + idx[kk]) & (L_ - 1);
    const half4 x = *reinterpret_cast<const half4*>(v + ((size_t)(b << LOG2L) + src) * D_ + c * 4);
    acc0 = fmaf(w, (float)x[0], acc0);
    acc1 = fmaf(w, (float)x[1], acc1);
    acc2 = fmaf(w, (float)x[2], acc2);
    acc3 = fmaf(w, (float)x[3], acc3);
  }
  half4 o;
  o[0] = (_Float16)acc0; o[1] = (_Float16)acc1;
  o[2] = (_Float16)acc2; o[3] = (_Float16)acc3;
  *reinterpret_cast<half4*>(ctx + ((size_t)(b << LOG2L) + l) * D_ + c * 4) = o;
}

// ------------------------------------------------------------------
extern "C" void kernel_launch(void* const* d_in, const int* in_sizes, int n_in,
                              void* d_out, int out_size, void* d_ws, size_t ws_size,
                              hipStream_t stream)
{
  (void)in_sizes; (void)n_in; (void)out_size; (void)ws_size;
  const float* Q   = (const float*)d_in[0];
  const float* K   = (const float*)d_in[1];
  const float* V   = (const float*)d_in[2];
  const float* WQ  = (const float*)d_in[3];
  const float* WK  = (const float*)d_in[4];
  const float* WV  = (const float*)d_in[5];
  const float* Wfc = (const float*)d_in[6];
  float* out = (float*)d_out;

  char* ws = (char*)d_ws;
  const size_t sz_mat = (size_t)M_ * D_ * sizeof(float);       // 33.55 MB
  const size_t sz_w16 = (size_t)D_ * D_ * sizeof(_Float16);    // 512 KB
  float*     qT    = (float*)(ws);                             // later: vs16
  float*     kT    = (float*)(ws + sz_mat);                    // later: ctx16
  _Float16*  WQt   = (_Float16*)(ws + 2 * sz_mat);
  _Float16*  WKt   = (_Float16*)(ws + 2 * sz_mat + sz_w16);
  _Float16*  WVt   = (_Float16*)(ws + 2 * sz_mat + 2 * sz_w16);
  _Float16*  Wfct  = (_Float16*)(ws + 2 * sz_mat + 3 * sz_w16);
  float*     S     = (float*)(ws + 2 * sz_mat + 4 * sz_w16);
  float*     mv    = (float*)((char*)S + (size_t)B_ * L_ * 2 * sizeof(float));
  int*       idx   = (int*)((char*)mv + (size_t)B_ * L_ * sizeof(float));
  float*     wts   = (float*)((char*)idx + 64);
  _Float16*  vs16  = (_Float16*)qT;     // overlays qT (dead after corr_fft)
  _Float16*  ctx16 = (_Float16*)kT;     // overlays kT (dead after corr_fft)

  convw_kernel<<<64, 256, 0, stream>>>(WQ, WQt);
  convw_kernel<<<64, 256, 0, stream>>>(WK, WKt);
  convw_kernel<<<64, 256, 0, stream>>>(WV, WVt);
  convw_kernel<<<64, 256, 0, stream>>>(Wfc, Wfct);

  gemm_f16_kernel<0, 1><<<512, 256, 0, stream>>>(Q, nullptr, WQt, qT, nullptr);
  gemm_f16_kernel<0, 1><<<512, 256, 0, stream>>>(K, nullptr, WKt, kT, nullptr);

  hipMemsetAsync(S, 0, (size_t)B_ * L_ * 2 * sizeof(float), stream);
  corr_fft_kernel<<<B_ * (D_ / DCHUNK), 256, 0, stream>>>(qT, kT, S);
  ifft_kernel<<<B_, 256, 0, stream>>>(S, mv);
  topk_kernel<<<1, 1024, 0, stream>>>(mv, idx, wts);

  gemm_f16_kernel<0, 2><<<512, 256, 0, stream>>>(V, nullptr, WVt, nullptr, vs16);
  context_kernel<<<B_ * L_, 128, 0, stream>>>(vs16, idx, wts, ctx16);
  gemm_f16_kernel<1, 0><<<512, 256, 0, stream>>>(nullptr, ctx16, Wfct, out, nullptr);
}

// Round 4
// 207.721 us; speedup vs baseline: 4.2888x; 1.9944x over previous
//
#include <hip/hip_runtime.h>
#include <math.h>

#define B_ 8
#define L_ 2048
#define D_ 512
#define LOG2L 11
#define TOPK 7
#define M_ (B_ * L_)     // 16384

typedef __attribute__((ext_vector_type(8))) _Float16 half8;
typedef __attribute__((ext_vector_type(4))) _Float16 half4;
typedef __attribute__((ext_vector_type(4))) float f32x4;

// ------------------------------------------------------------------
// convw: W fp32 [512][512] row-major (k-major) -> Wt f16 [512][512]
// with Wt[n][k] = W[k][n]. 64x64 tiles via LDS.
// ------------------------------------------------------------------
__global__ __launch_bounds__(256) void convw_kernel(
    const float* __restrict__ W, _Float16* __restrict__ Wt)
{
  __shared__ float tile[64][65];
  const int t = (int)threadIdx.x;
  const int k0 = ((int)blockIdx.x >> 3) * 64;
  const int n0 = ((int)blockIdx.x & 7) * 64;
#pragma unroll
  for (int i = 0; i < 4; ++i) {
    const int kl = (t >> 4) + i * 16;
    const float4 v = *reinterpret_cast<const float4*>(&W[(size_t)(k0 + kl) * D_ + n0 + (t & 15) * 4]);
    tile[kl][(t & 15) * 4 + 0] = v.x;
    tile[kl][(t & 15) * 4 + 1] = v.y;
    tile[kl][(t & 15) * 4 + 2] = v.z;
    tile[kl][(t & 15) * 4 + 3] = v.w;
  }
  __syncthreads();
  const int nl = t >> 2, q = t & 3;
  half8 h0, h1;
#pragma unroll
  for (int j = 0; j < 8; ++j) {
    h0[j] = (_Float16)tile[q * 16 + j][nl];
    h1[j] = (_Float16)tile[q * 16 + 8 + j][nl];
  }
  _Float16* dst = &Wt[(size_t)(n0 + nl) * D_ + k0 + q * 16];
  *reinterpret_cast<half8*>(dst) = h0;
  *reinterpret_cast<half8*>(dst + 8) = h1;
}

// ------------------------------------------------------------------
// MFMA f16 GEMM: C = A[M,512] @ W[512,512] using Wt[n][k] f16.
// 128x128 tile, BK=32, 256 thr = 4 waves (2x2), wave tile 64x64.
// INBF: 0 = A fp32 (convert in staging), 1 = A f16.
// OUTMODE: 0 = fp32 [M,512]; 1 = fp32 transposed [512][M] (direct
// float4 stores -- acc reg index IS the m dimension); 2 = f16 [M,512].
// ------------------------------------------------------------------
#define LDSTR 40

template <int INBF, int OUTMODE>
__global__ __launch_bounds__(256) void gemm_f16_kernel(
    const float* __restrict__ Af, const _Float16* __restrict__ Ah,
    const _Float16* __restrict__ Wt,
    float* __restrict__ Cf, _Float16* __restrict__ Ch)
{
  __shared__ __align__(16) char smem[128 * LDSTR * 2 * 2];   // 20480 B
  _Float16* sA = (_Float16*)smem;
  _Float16* sB = sA + 128 * LDSTR;

  const int tid = (int)threadIdx.x;
  const int lane = tid & 63, wave = tid >> 6;
  const int wr = (wave >> 1) << 6, wc = (wave & 1) << 6;
  const int m0 = ((int)blockIdx.x >> 2) << 7;
  const int n0 = ((int)blockIdx.x & 3) << 7;

  const int srow = tid >> 1;            // 0..127
  const int sc0 = (tid & 1) << 4;       // 0 / 16

  f32x4 acc[4][4];
  const f32x4 zero = {0.f, 0.f, 0.f, 0.f};
#pragma unroll
  for (int i = 0; i < 4; ++i)
#pragma unroll
    for (int j = 0; j < 4; ++j) acc[i][j] = zero;

  const int fr = lane & 15;
  const int g8 = (lane >> 4) << 3;

  for (int k0 = 0; k0 < D_; k0 += 32) {
    half8 ha0, ha1, hb0, hb1;
    if constexpr (INBF == 0) {
      const float* ap = Af + (size_t)(m0 + srow) * D_ + k0 + sc0;
      float tmp[16];
#pragma unroll
      for (int j = 0; j < 4; ++j) {
        const float4 v = *reinterpret_cast<const float4*>(ap + j * 4);
        tmp[j * 4 + 0] = v.x; tmp[j * 4 + 1] = v.y;
        tmp[j * 4 + 2] = v.z; tmp[j * 4 + 3] = v.w;
      }
#pragma unroll
      for (int j = 0; j < 8; ++j) { ha0[j] = (_Float16)tmp[j]; ha1[j] = (_Float16)tmp[8 + j]; }
    } else {
      const _Float16* ap = Ah + (size_t)(m0 + srow) * D_ + k0 + sc0;
      ha0 = *reinterpret_cast<const half8*>(ap);
      ha1 = *reinterpret_cast<const half8*>(ap + 8);
    }
    {
      const _Float16* bp = Wt + (size_t)(n0 + srow) * D_ + k0 + sc0;
      hb0 = *reinterpret_cast<const half8*>(bp);
      hb1 = *reinterpret_cast<const half8*>(bp + 8);
    }

    __syncthreads();    // previous iteration's fragment reads done
    *reinterpret_cast<half8*>(&sA[srow * LDSTR + sc0]) = ha0;
    *reinterpret_cast<half8*>(&sA[srow * LDSTR + sc0 + 8]) = ha1;
    *reinterpret_cast<half8*>(&sB[srow * LDSTR + sc0]) = hb0;
    *reinterpret_cast<half8*>(&sB[srow * LDSTR + sc0 + 8]) = hb1;
    __syncthreads();

    half8 afr[4], bfr[4];
#pragma unroll
    for (int i = 0; i < 4; ++i) {
      afr[i] = *reinterpret_cast<const half8*>(&sA[(wr + i * 16 + fr) * LDSTR + g8]);
      bfr[i] = *reinterpret_cast<const half8*>(&sB[(wc + i * 16 + fr) * LDSTR + g8]);
    }
#pragma unroll
    for (int mi = 0; mi < 4; ++mi)
#pragma unroll
      for (int ni = 0; ni < 4; ++ni)
        acc[mi][ni] = __builtin_amdgcn_mfma_f32_16x16x32_f16(afr[mi], bfr[ni], acc[mi][ni], 0, 0, 0);
  }

  const int orow = (lane >> 4) << 2;   // m sub-offset (reg idx r adds 0..3)
  const int ocol = lane & 15;          // n sub-offset
  if constexpr (OUTMODE == 0) {
#pragma unroll
    for (int mi = 0; mi < 4; ++mi)
#pragma unroll
      for (int ni = 0; ni < 4; ++ni)
#pragma unroll
        for (int r = 0; r < 4; ++r)
          Cf[(size_t)(m0 + wr + mi * 16 + orow + r) * D_ + n0 + wc + ni * 16 + ocol] = acc[mi][ni][r];
  } else if constexpr (OUTMODE == 2) {
#pragma unroll
    for (int mi = 0; mi < 4; ++mi)
#pragma unroll
      for (int ni = 0; ni < 4; ++ni)
#pragma unroll
        for (int r = 0; r < 4; ++r)
          Ch[(size_t)(m0 + wr + mi * 16 + orow + r) * D_ + n0 + wc + ni * 16 + ocol] = (_Float16)acc[mi][ni][r];
  } else {
    // CT[n][m]: acc[mi][ni] holds 4 consecutive m values -> direct float4
#pragma unroll
    for (int ni = 0; ni < 4; ++ni) {
      const size_t nrow = (size_t)(n0 + wc + ni * 16 + ocol) * M_;
#pragma unroll
      for (int mi = 0; mi < 4; ++mi) {
        const float4 vv = {acc[mi][ni][0], acc[mi][ni][1], acc[mi][ni][2], acc[mi][ni][3]};
        *reinterpret_cast<float4*>(&Cf[nrow + m0 + wr + mi * 16 + orow]) = vv;
      }
    }
  }
}

// ------------------------------------------------------------------
// In-LDS radix-2 2048-pt FFT pieces (verified R2).
// ------------------------------------------------------------------
__device__ __forceinline__ int rev11(int x) {
  return (int)(__brev((unsigned)x) >> (32 - LOG2L));
}

#define DCHUNK 4

__global__ __launch_bounds__(256) void corr_fft_kernel(
    const float* __restrict__ qT, const float* __restrict__ kT,
    float* __restrict__ S)
{
  __shared__ float re[L_];
  __shared__ float im[L_];
  __shared__ float twr[L_];
  __shared__ float twi[L_];
  const int tid = (int)threadIdx.x;
  const int blk = (int)blockIdx.x;
  const int b = blk >> 7;
  const int d0 = (blk & 127) * DCHUNK;

  for (int t = tid; t < L_; t += 256) {
    if (t == 0) { twr[0] = 1.f; twi[0] = 0.f; continue; }
    const int h = 31 - __clz((unsigned)t);
    const int half = 1 << h;
    const int pos = t - half;
    const float ang = -3.14159265358979323846f * (float)pos / (float)half;
    float si, co;
    __sincosf(ang, &si, &co);
    twr[t] = co; twi[t] = si;
  }

  float pr[8] = {}, pi_[8] = {};

  for (int dc = 0; dc < DCHUNK; ++dc) {
    const int d = d0 + dc;
    const float* qrow = qT + (size_t)d * M_ + (size_t)b * L_;
    const float* krow = kT + (size_t)d * M_ + (size_t)b * L_;
    __syncthreads();
    for (int t = tid * 4; t < L_; t += 1024) {
      float4 qv = *reinterpret_cast<const float4*>(qrow + t);
      float4 kv = *reinterpret_cast<const float4*>(krow + t);
      re[t + 0] = qv.x; re[t + 1] = qv.y; re[t + 2] = qv.z; re[t + 3] = qv.w;
      im[t + 0] = kv.x; im[t + 1] = kv.y; im[t + 2] = kv.z; im[t + 3] = kv.w;
    }
    __syncthreads();

    for (int s = LOG2L; s >= 1; --s) {
      const int half = 1 << (s - 1);
      for (int j = tid; j < (L_ >> 1); j += 256) {
        const int pos = j & (half - 1);
        const int i0 = ((j >> (s - 1)) << s) + pos;
        const int i1 = i0 + half;
        const float ar = re[i0], ai = im[i0];
        const float br = re[i1], bi = im[i1];
        re[i0] = ar + br; im[i0] = ai + bi;
        const float tr = ar - br, ti = ai - bi;
        const float wr = twr[half + pos], wi = twi[half + pos];
        re[i1] = tr * wr - ti * wi;
        im[i1] = tr * wi + ti * wr;
      }
      __syncthreads();
    }

#pragma unroll
    for (int i = 0; i < 8; ++i) {
      const int p = tid + 256 * i;
      const int f = rev11(p);
      const int fm = (L_ - f) & (L_ - 1);
      const int pm = rev11(fm);
      const float Ar = re[p],  Ai = im[p];
      const float Br = re[pm], Bi = -im[pm];
      const float Qr = 0.5f * (Ar + Br), Qi = 0.5f * (Ai + Bi);
      const float Cr = 0.5f * (Ai - Bi), Ci = 0.5f * (Ar - Br);
      pr[i]  += Qr * Cr - Qi * Ci;
      pi_[i] += Qr * Ci + Qi * Cr;
    }
  }

#pragma unroll
  for (int i = 0; i < 8; ++i) {
    const int p = tid + 256 * i;
    atomicAdd(&S[((size_t)b * L_ + p) * 2 + 0], pr[i]);
    atomicAdd(&S[((size_t)b * L_ + p) * 2 + 1], pi_[i]);
  }
}

__global__ __launch_bounds__(256) void ifft_kernel(
    const float* __restrict__ S, float* __restrict__ mv)
{
  __shared__ float re[L_];
  __shared__ float im[L_];
  const int b = blockIdx.x;
  for (int p = (int)threadIdx.x; p < L_; p += 256) {
    re[p] = S[((size_t)b * L_ + p) * 2 + 0];
    im[p] = S[((size_t)b * L_ + p) * 2 + 1];
  }
  __syncthreads();
  for (int s = 1; s <= LOG2L; ++s) {
    const int half = 1 << (s - 1);
    for (int j = (int)threadIdx.x; j < (L_ >> 1); j += 256) {
      const int pos = j & (half - 1);
      const int i0 = ((j >> (s - 1)) << s) + pos;
      const int i1 = i0 + half;
      const float ang = 3.14159265358979323846f * (float)pos / (float)half;
      float wi, wr;
      __sincosf(ang, &wi, &wr);
      const float br = re[i1], bi = im[i1];
      const float tr = br * wr - bi * wi;
      const float ti = br * wi + bi * wr;
      const float ar = re[i0], ai = im[i0];
      re[i0] = ar + tr; im[i0] = ai + ti;
      re[i1] = ar - tr; im[i1] = ai - ti;
    }
    __syncthreads();
  }
  const float scale = 1.0f / ((float)D_ * (float)L_);
  for (int l = (int)threadIdx.x; l < L_; l += 256)
    mv[(size_t)b * L_ + l] = re[l] * scale;
}

// ------------------------------------------------------------------
// topk: 1024 threads, shuffle-reduce argmax x7, then softmax.
// ------------------------------------------------------------------
__global__ __launch_bounds__(1024) void topk_kernel(
    const float* __restrict__ mv, int* __restrict__ idx, float* __restrict__ wts)
{
  __shared__ float vals[L_];
  __shared__ float wm[16];
  __shared__ int wi[16];
  __shared__ int chosen[TOPK];
  const int t = (int)threadIdx.x;
  const int lane = t & 63, wv = t >> 6;
  float s0 = 0.f, s1 = 0.f;
#pragma unroll
  for (int b = 0; b < B_; ++b) {
    s0 += mv[(size_t)b * L_ + t];
    s1 += mv[(size_t)b * L_ + t + 1024];
  }
  vals[t] = s0; vals[t + 1024] = s1;
  __syncthreads();
  for (int kk = 0; kk < TOPK; ++kk) {
    float v0 = vals[t]; int i0 = t;
    const float v1 = vals[t + 1024];
    if (v1 > v0) { v0 = v1; i0 = t + 1024; }
#pragma unroll
    for (int off = 32; off; off >>= 1) {
      const float ov = __shfl_xor(v0, off, 64);
      const int oi = __shfl_xor(i0, off, 64);
      if (ov > v0 || (ov == v0 && oi < i0)) { v0 = ov; i0 = oi; }
    }
    if (lane == 0) { wm[wv] = v0; wi[wv] = i0; }
    __syncthreads();
    if (t == 0) {
      float m = wm[0]; int mi = wi[0];
      for (int i2 = 1; i2 < 16; ++i2)
        if (wm[i2] > m || (wm[i2] == m && wi[i2] < mi)) { m = wm[i2]; mi = wi[i2]; }
      chosen[kk] = mi; idx[kk] = mi; vals[mi] = -1e30f;
    }
    __syncthreads();
  }
  if (t < B_) {
    float w[TOPK];
    float mx = -1e30f;
#pragma unroll
    for (int kk = 0; kk < TOPK; ++kk) {
      w[kk] = mv[(size_t)t * L_ + chosen[kk]];
      mx = fmaxf(mx, w[kk]);
    }
    float sum = 0.f;
#pragma unroll
    for (int kk = 0; kk < TOPK; ++kk) { w[kk] = __expf(w[kk] - mx); sum += w[kk]; }
    const float inv = 1.0f / sum;
#pragma unroll
    for (int kk = 0; kk < TOPK; ++kk) wts[t * TOPK + kk] = w[kk] * inv;
  }
}

// ------------------------------------------------------------------
// context: f16 in, f16 out. ctx[b,l,:] = sum_k w[b,k]*v[b,(l+idx[k])%L,:]
// ------------------------------------------------------------------
__global__ __launch_bounds__(128) void context_kernel(
    const _Float16* __restrict__ v, const int* __restrict__ idx,
    const float* __restrict__ wts, _Float16* __restrict__ ctx)
{
  const int bl = (int)blockIdx.x;
  const int b = bl >> LOG2L;
  const int l = bl & (L_ - 1);
  const int c = (int)threadIdx.x;     // half4 lane
  float acc0 = 0.f, acc1 = 0.f, acc2 = 0.f, acc3 = 0.f;
#pragma unroll
  for (int kk = 0; kk < TOPK; ++kk) {
    const float w = wts[b * TOPK + kk];
    const int src = (l + idx[kk]) & (L_ - 1);
    const half4 x = *reinterpret_cast<const half4*>(v + ((size_t)(b << LOG2L) + src) * D_ + c * 4);
    acc0 = fmaf(w, (float)x[0], acc0);
    acc1 = fmaf(w, (float)x[1], acc1);
    acc2 = fmaf(w, (float)x[2], acc2);
    acc3 = fmaf(w, (float)x[3], acc3);
  }
  half4 o;
  o[0] = (_Float16)acc0; o[1] = (_Float16)acc1;
  o[2] = (_Float16)acc2; o[3] = (_Float16)acc3;
  *reinterpret_cast<half4*>(ctx + ((size_t)(b << LOG2L) + l) * D_ + c * 4) = o;
}

// ------------------------------------------------------------------
extern "C" void kernel_launch(void* const* d_in, const int* in_sizes, int n_in,
                              void* d_out, int out_size, void* d_ws, size_t ws_size,
                              hipStream_t stream)
{
  (void)in_sizes; (void)n_in; (void)out_size; (void)ws_size;
  const float* Q   = (const float*)d_in[0];
  const float* K   = (const float*)d_in[1];
  const float* V   = (const float*)d_in[2];
  const float* WQ  = (const float*)d_in[3];
  const float* WK  = (const float*)d_in[4];
  const float* WV  = (const float*)d_in[5];
  const float* Wfc = (const float*)d_in[6];
  float* out = (float*)d_out;

  char* ws = (char*)d_ws;
  const size_t sz_mat = (size_t)M_ * D_ * sizeof(float);       // 33.55 MB
  const size_t sz_w16 = (size_t)D_ * D_ * sizeof(_Float16);    // 512 KB
  float*     qT    = (float*)(ws);                             // later: vs16
  float*     kT    = (float*)(ws + sz_mat);                    // later: ctx16
  _Float16*  WQt   = (_Float16*)(ws + 2 * sz_mat);
  _Float16*  WKt   = (_Float16*)(ws + 2 * sz_mat + sz_w16);
  _Float16*  WVt   = (_Float16*)(ws + 2 * sz_mat + 2 * sz_w16);
  _Float16*  Wfct  = (_Float16*)(ws + 2 * sz_mat + 3 * sz_w16);
  float*     S     = (float*)(ws + 2 * sz_mat + 4 * sz_w16);
  float*     mv    = (float*)((char*)S + (size_t)B_ * L_ * 2 * sizeof(float));
  int*       idx   = (int*)((char*)mv + (size_t)B_ * L_ * sizeof(float));
  float*     wts   = (float*)((char*)idx + 64);
  _Float16*  vs16  = (_Float16*)qT;     // overlays qT (dead after corr_fft)
  _Float16*  ctx16 = (_Float16*)kT;     // overlays kT (dead after corr_fft)

  convw_kernel<<<64, 256, 0, stream>>>(WQ, WQt);
  convw_kernel<<<64, 256, 0, stream>>>(WK, WKt);
  convw_kernel<<<64, 256, 0, stream>>>(WV, WVt);
  convw_kernel<<<64, 256, 0, stream>>>(Wfc, Wfct);

  gemm_f16_kernel<0, 1><<<512, 256, 0, stream>>>(Q, nullptr, WQt, qT, nullptr);
  gemm_f16_kernel<0, 1><<<512, 256, 0, stream>>>(K, nullptr, WKt, kT, nullptr);

  hipMemsetAsync(S, 0, (size_t)B_ * L_ * 2 * sizeof(float), stream);
  corr_fft_kernel<<<B_ * (D_ / DCHUNK), 256, 0, stream>>>(qT, kT, S);
  ifft_kernel<<<B_, 256, 0, stream>>>(S, mv);
  topk_kernel<<<1, 1024, 0, stream>>>(mv, idx, wts);

  gemm_f16_kernel<0, 2><<<512, 256, 0, stream>>>(V, nullptr, WVt, nullptr, vs16);
  context_kernel<<<B_ * L_, 128, 0, stream>>>(vs16, idx, wts, ctx16);
  gemm_f16_kernel<1, 0><<<512, 256, 0, stream>>>(nullptr, ctx16, Wfct, out, nullptr);
}

// Round 5
// 182.895 us; speedup vs baseline: 4.8709x; 1.1357x over previous
//
#include <hip/hip_runtime.h>
#include <math.h>

#define B_ 8
#define L_ 2048
#define D_ 512
#define LOG2L 11
#define TOPK 7
#define M_ (B_ * L_)     // 16384

typedef __attribute__((ext_vector_type(8))) _Float16 half8;
typedef __attribute__((ext_vector_type(4))) _Float16 half4;
typedef __attribute__((ext_vector_type(4))) float f32x4;

// ------------------------------------------------------------------
// convw: 4 weight mats fp32 [512][512] (k-major) -> f16 [n][k]. One
// launch; blockIdx>>6 selects the matrix.
// ------------------------------------------------------------------
__global__ __launch_bounds__(256) void convw_kernel(
    const float* __restrict__ W0, const float* __restrict__ W1,
    const float* __restrict__ W2, const float* __restrict__ W3,
    _Float16* __restrict__ T0, _Float16* __restrict__ T1,
    _Float16* __restrict__ T2, _Float16* __restrict__ T3)
{
  __shared__ float tile[64][65];
  const int t = (int)threadIdx.x;
  const int mat = (int)blockIdx.x >> 6;
  const int tb = (int)blockIdx.x & 63;
  const float* W = (mat == 0) ? W0 : (mat == 1) ? W1 : (mat == 2) ? W2 : W3;
  _Float16* Wt = (mat == 0) ? T0 : (mat == 1) ? T1 : (mat == 2) ? T2 : T3;
  const int k0 = (tb >> 3) * 64;
  const int n0 = (tb & 7) * 64;
#pragma unroll
  for (int i = 0; i < 4; ++i) {
    const int kl = (t >> 4) + i * 16;
    const float4 v = *reinterpret_cast<const float4*>(&W[(size_t)(k0 + kl) * D_ + n0 + (t & 15) * 4]);
    tile[kl][(t & 15) * 4 + 0] = v.x;
    tile[kl][(t & 15) * 4 + 1] = v.y;
    tile[kl][(t & 15) * 4 + 2] = v.z;
    tile[kl][(t & 15) * 4 + 3] = v.w;
  }
  __syncthreads();
  const int nl = t >> 2, q = t & 3;
  half8 h0, h1;
#pragma unroll
  for (int j = 0; j < 8; ++j) {
    h0[j] = (_Float16)tile[q * 16 + j][nl];
    h1[j] = (_Float16)tile[q * 16 + 8 + j][nl];
  }
  _Float16* dst = &Wt[(size_t)(n0 + nl) * D_ + k0 + q * 16];
  *reinterpret_cast<half8*>(dst) = h0;
  *reinterpret_cast<half8*>(dst + 8) = h1;
}

// ------------------------------------------------------------------
// MFMA f16 GEMM: C = A[M,512] @ W using Wt[n][k] f16. 128x128 tile,
// BK=32, 4 waves. OUTMODE: 0 = fp32 [M,512]; 2 = f16 [M,512];
// 3 = f16 transposed [512][M] (acc reg idx is m -> half4 direct store).
// ------------------------------------------------------------------
#define LDSTR 40

template <int INBF, int OUTMODE>
__global__ __launch_bounds__(256) void gemm_f16_kernel(
    const float* __restrict__ Af, const _Float16* __restrict__ Ah,
    const _Float16* __restrict__ Wt,
    float* __restrict__ Cf, _Float16* __restrict__ Ch)
{
  __shared__ __align__(16) char smem[128 * LDSTR * 2 * 2];   // 20480 B
  _Float16* sA = (_Float16*)smem;
  _Float16* sB = sA + 128 * LDSTR;

  const int tid = (int)threadIdx.x;
  const int lane = tid & 63, wave = tid >> 6;
  const int wr = (wave >> 1) << 6, wc = (wave & 1) << 6;
  const int m0 = ((int)blockIdx.x >> 2) << 7;
  const int n0 = ((int)blockIdx.x & 3) << 7;

  const int srow = tid >> 1;            // 0..127
  const int sc0 = (tid & 1) << 4;       // 0 / 16

  f32x4 acc[4][4];
  const f32x4 zero = {0.f, 0.f, 0.f, 0.f};
#pragma unroll
  for (int i = 0; i < 4; ++i)
#pragma unroll
    for (int j = 0; j < 4; ++j) acc[i][j] = zero;

  const int fr = lane & 15;
  const int g8 = (lane >> 4) << 3;

  for (int k0 = 0; k0 < D_; k0 += 32) {
    half8 ha0, ha1, hb0, hb1;
    if constexpr (INBF == 0) {
      const float* ap = Af + (size_t)(m0 + srow) * D_ + k0 + sc0;
      float tmp[16];
#pragma unroll
      for (int j = 0; j < 4; ++j) {
        const float4 v = *reinterpret_cast<const float4*>(ap + j * 4);
        tmp[j * 4 + 0] = v.x; tmp[j * 4 + 1] = v.y;
        tmp[j * 4 + 2] = v.z; tmp[j * 4 + 3] = v.w;
      }
#pragma unroll
      for (int j = 0; j < 8; ++j) { ha0[j] = (_Float16)tmp[j]; ha1[j] = (_Float16)tmp[8 + j]; }
    } else {
      const _Float16* ap = Ah + (size_t)(m0 + srow) * D_ + k0 + sc0;
      ha0 = *reinterpret_cast<const half8*>(ap);
      ha1 = *reinterpret_cast<const half8*>(ap + 8);
    }
    {
      const _Float16* bp = Wt + (size_t)(n0 + srow) * D_ + k0 + sc0;
      hb0 = *reinterpret_cast<const half8*>(bp);
      hb1 = *reinterpret_cast<const half8*>(bp + 8);
    }

    __syncthreads();
    *reinterpret_cast<half8*>(&sA[srow * LDSTR + sc0]) = ha0;
    *reinterpret_cast<half8*>(&sA[srow * LDSTR + sc0 + 8]) = ha1;
    *reinterpret_cast<half8*>(&sB[srow * LDSTR + sc0]) = hb0;
    *reinterpret_cast<half8*>(&sB[srow * LDSTR + sc0 + 8]) = hb1;
    __syncthreads();

    half8 afr[4], bfr[4];
#pragma unroll
    for (int i = 0; i < 4; ++i) {
      afr[i] = *reinterpret_cast<const half8*>(&sA[(wr + i * 16 + fr) * LDSTR + g8]);
      bfr[i] = *reinterpret_cast<const half8*>(&sB[(wc + i * 16 + fr) * LDSTR + g8]);
    }
#pragma unroll
    for (int mi = 0; mi < 4; ++mi)
#pragma unroll
      for (int ni = 0; ni < 4; ++ni)
        acc[mi][ni] = __builtin_amdgcn_mfma_f32_16x16x32_f16(afr[mi], bfr[ni], acc[mi][ni], 0, 0, 0);
  }

  const int orow = (lane >> 4) << 2;   // m sub-offset (reg idx r adds 0..3)
  const int ocol = lane & 15;          // n sub-offset
  if constexpr (OUTMODE == 0) {
#pragma unroll
    for (int mi = 0; mi < 4; ++mi)
#pragma unroll
      for (int ni = 0; ni < 4; ++ni)
#pragma unroll
        for (int r = 0; r < 4; ++r)
          Cf[(size_t)(m0 + wr + mi * 16 + orow + r) * D_ + n0 + wc + ni * 16 + ocol] = acc[mi][ni][r];
  } else if constexpr (OUTMODE == 2) {
#pragma unroll
    for (int mi = 0; mi < 4; ++mi)
#pragma unroll
      for (int ni = 0; ni < 4; ++ni)
#pragma unroll
        for (int r = 0; r < 4; ++r)
          Ch[(size_t)(m0 + wr + mi * 16 + orow + r) * D_ + n0 + wc + ni * 16 + ocol] = (_Float16)acc[mi][ni][r];
  } else {
    // CT[n][m] f16: acc[mi][ni] holds 4 consecutive m -> half4 store
#pragma unroll
    for (int ni = 0; ni < 4; ++ni) {
      const size_t nrow = (size_t)(n0 + wc + ni * 16 + ocol) * M_;
#pragma unroll
      for (int mi = 0; mi < 4; ++mi) {
        half4 hv;
        hv[0] = (_Float16)acc[mi][ni][0]; hv[1] = (_Float16)acc[mi][ni][1];
        hv[2] = (_Float16)acc[mi][ni][2]; hv[3] = (_Float16)acc[mi][ni][3];
        *reinterpret_cast<half4*>(&Ch[nrow + m0 + wr + mi * 16 + orow]) = hv;
      }
    }
  }
}

// ------------------------------------------------------------------
// corr_fft v3: 4-round register FFT (radix-8 per round via 3 fused
// radix-2 stages). Each thread holds 8 complex elems; 3 LDS exchanges
// + final write. DIF: natural in -> bit-reversed out. f16 input.
// ------------------------------------------------------------------
__device__ __forceinline__ int rev11(int x) {
  return (int)(__brev((unsigned)x) >> (32 - LOG2L));
}

#define DCHUNK 4
#define PADI(i) ((i) + ((i) >> 5))

#define BFLY(j0, j1, wr_, wi_) { \
  const float ar = xr[j0], ai = xi[j0], br = xr[j1], bi = xi[j1]; \
  xr[j0] = ar + br; xi[j0] = ai + bi; \
  const float tr = ar - br, ti = ai - bi; \
  xr[j1] = tr * (wr_) - ti * (wi_); \
  xi[j1] = tr * (wi_) + ti * (wr_); }

__global__ __launch_bounds__(256) void corr_fft_kernel(
    const _Float16* __restrict__ qT, const _Float16* __restrict__ kT,
    float* __restrict__ S)
{
  __shared__ float re[2112];
  __shared__ float im[2112];
  const int t = (int)threadIdx.x;
  const int blk = (int)blockIdx.x;
  const int b = blk >> 7;
  const int d0 = (blk & 127) * DCHUNK;
  const int u2 = t & 31, u3 = t & 3;

  // base twiddles: W_N^k = exp(-2*pi*i*k/N); derive halves by squaring
  float w2048r, w2048i, w256r, w256i, w32r, w32i;
  {
    float s_, c_;
    __sincosf(-6.283185307179586f * (float)t / 2048.f, &s_, &c_);
    w2048r = c_; w2048i = s_;
    __sincosf(-6.283185307179586f * (float)u2 / 256.f, &s_, &c_);
    w256r = c_; w256i = s_;
    __sincosf(-6.283185307179586f * (float)u3 / 32.f, &s_, &c_);
    w32r = c_; w32i = s_;
  }
  const float w1024r = w2048r * w2048r - w2048i * w2048i, w1024i = 2.f * w2048r * w2048i;
  const float w512r  = w1024r * w1024r - w1024i * w1024i, w512i  = 2.f * w1024r * w1024i;
  const float w128r  = w256r * w256r - w256i * w256i,     w128i  = 2.f * w256r * w256i;
  const float w64r   = w128r * w128r - w128i * w128i,     w64i   = 2.f * w128r * w128i;
  const float w16r   = w32r * w32r - w32i * w32i,         w16i   = 2.f * w32r * w32i;
  const float w8r    = w16r * w16r - w16i * w16i,         w8i    = 2.f * w16r * w16i;

  const float C_ = 0.70710678118654752f;
  const float W8R[4] = {1.f, C_, 0.f, -C_};
  const float W8I[4] = {0.f, -C_, -1.f, -C_};

  float pr[8] = {}, pi_[8] = {};

  for (int dc = 0; dc < DCHUNK; ++dc) {
    const int d = d0 + dc;
    const _Float16* qrow = qT + (size_t)d * M_ + (size_t)b * L_;
    const _Float16* krow = kT + (size_t)d * M_ + (size_t)b * L_;

    float xr[8], xi[8];
#pragma unroll
    for (int j = 0; j < 8; ++j) {
      xr[j] = (float)qrow[t + 256 * j];
      xi[j] = (float)krow[t + 256 * j];
    }

    // ---- round 1: stages half=1024,512,256 (elem j at pos t+256j)
#pragma unroll
    for (int j = 0; j < 4; ++j) {
      const float wr_ = w2048r * W8R[j] - w2048i * W8I[j];
      const float wi_ = w2048r * W8I[j] + w2048i * W8R[j];
      BFLY(j, j + 4, wr_, wi_);
    }
#pragma unroll
    for (int base = 0; base < 8; base += 4) {
      BFLY(base + 0, base + 2, w1024r, w1024i);
      BFLY(base + 1, base + 3, w1024i, -w1024r);   // * W_4^1 = -i
    }
#pragma unroll
    for (int a = 0; a < 8; a += 2) BFLY(a, a + 1, w512r, w512i);

    // ---- exchange 1: pos t+256j -> pos (t>>5)*256 + (t&31) + 32j
    __syncthreads();   // prior product reads done
#pragma unroll
    for (int j = 0; j < 8; ++j) {
      const int p = t + 256 * j;
      re[PADI(p)] = xr[j]; im[PADI(p)] = xi[j];
    }
    __syncthreads();
#pragma unroll
    for (int j = 0; j < 8; ++j) {
      const int p = ((t >> 5) << 8) + u2 + 32 * j;
      xr[j] = re[PADI(p)]; xi[j] = im[PADI(p)];
    }

    // ---- round 2: stages half=128,64,32
#pragma unroll
    for (int j = 0; j < 4; ++j) {
      const float wr_ = w256r * W8R[j] - w256i * W8I[j];
      const float wi_ = w256r * W8I[j] + w256i * W8R[j];
      BFLY(j, j + 4, wr_, wi_);
    }
#pragma unroll
    for (int base = 0; base < 8; base += 4) {
      BFLY(base + 0, base + 2, w128r, w128i);
      BFLY(base + 1, base + 3, w128i, -w128r);
    }
#pragma unroll
    for (int a = 0; a < 8; a += 2) BFLY(a, a + 1, w64r, w64i);

    // ---- exchange 2 -> pos (t>>2)*32 + (t&3) + 4j
    __syncthreads();
#pragma unroll
    for (int j = 0; j < 8; ++j) {
      const int p = ((t >> 5) << 8) + u2 + 32 * j;
      re[PADI(p)] = xr[j]; im[PADI(p)] = xi[j];
    }
    __syncthreads();
#pragma unroll
    for (int j = 0; j < 8; ++j) {
      const int p = ((t >> 2) << 5) + u3 + 4 * j;
      xr[j] = re[PADI(p)]; xi[j] = im[PADI(p)];
    }

    // ---- round 3: stages half=16,8,4
#pragma unroll
    for (int j = 0; j < 4; ++j) {
      const float wr_ = w32r * W8R[j] - w32i * W8I[j];
      const float wi_ = w32r * W8I[j] + w32i * W8R[j];
      BFLY(j, j + 4, wr_, wi_);
    }
#pragma unroll
    for (int base = 0; base < 8; base += 4) {
      BFLY(base + 0, base + 2, w16r, w16i);
      BFLY(base + 1, base + 3, w16i, -w16r);
    }
#pragma unroll
    for (int a = 0; a < 8; a += 2) BFLY(a, a + 1, w8r, w8i);

    // ---- exchange 3 -> pos 8t+j (contiguous)
    __syncthreads();
#pragma unroll
    for (int j = 0; j < 8; ++j) {
      const int p = ((t >> 2) << 5) + u3 + 4 * j;
      re[PADI(p)] = xr[j]; im[PADI(p)] = xi[j];
    }
    __syncthreads();
#pragma unroll
    for (int j = 0; j < 8; ++j) {
      const int p = 8 * t + j;
      xr[j] = re[PADI(p)]; xi[j] = im[PADI(p)];
    }

    // ---- round 4: stages half=2,1 (trivial twiddles)
#pragma unroll
    for (int base = 0; base < 8; base += 4) {
      BFLY(base + 0, base + 2, 1.f, 0.f);
      BFLY(base + 1, base + 3, 0.f, -1.f);
    }
#pragma unroll
    for (int a = 0; a < 8; a += 2) BFLY(a, a + 1, 1.f, 0.f);

    // ---- final write (in-place, thread-local positions)
#pragma unroll
    for (int j = 0; j < 8; ++j) {
      const int p = 8 * t + j;
      re[PADI(p)] = xr[j]; im[PADI(p)] = xi[j];
    }
    __syncthreads();

    // ---- Hermitian split + product (pos p holds freq rev11(p))
#pragma unroll
    for (int i = 0; i < 8; ++i) {
      const int p = t + 256 * i;
      const int f = rev11(p);
      const int fm = (L_ - f) & (L_ - 1);
      const int pm = rev11(fm);
      const float Ar = re[PADI(p)],  Ai = im[PADI(p)];
      const float Br = re[PADI(pm)], Bi = -im[PADI(pm)];
      const float Qr = 0.5f * (Ar + Br), Qi = 0.5f * (Ai + Bi);
      const float Cr = 0.5f * (Ai - Bi), Ci = 0.5f * (Ar - Br);
      pr[i]  += Qr * Cr - Qi * Ci;
      pi_[i] += Qr * Ci + Qi * Cr;
    }
  }

#pragma unroll
  for (int i = 0; i < 8; ++i) {
    const int p = t + 256 * i;
    atomicAdd(&S[((size_t)b * L_ + p) * 2 + 0], pr[i]);
    atomicAdd(&S[((size_t)b * L_ + p) * 2 + 1], pi_[i]);
  }
}

// ------------------------------------------------------------------
// Inverse DIT (bit-rev in, natural out), per b.
// ------------------------------------------------------------------
__global__ __launch_bounds__(256) void ifft_kernel(
    const float* __restrict__ S, float* __restrict__ mv)
{
  __shared__ float re[L_];
  __shared__ float im[L_];
  const int b = blockIdx.x;
  for (int p = (int)threadIdx.x; p < L_; p += 256) {
    re[p] = S[((size_t)b * L_ + p) * 2 + 0];
    im[p] = S[((size_t)b * L_ + p) * 2 + 1];
  }
  __syncthreads();
  for (int s = 1; s <= LOG2L; ++s) {
    const int half = 1 << (s - 1);
    for (int j = (int)threadIdx.x; j < (L_ >> 1); j += 256) {
      const int pos = j & (half - 1);
      const int i0 = ((j >> (s - 1)) << s) + pos;
      const int i1 = i0 + half;
      const float ang = 3.14159265358979323846f * (float)pos / (float)half;
      float wi, wr;
      __sincosf(ang, &wi, &wr);
      const float br = re[i1], bi = im[i1];
      const float tr = br * wr - bi * wi;
      const float ti = br * wi + bi * wr;
      const float ar = re[i0], ai = im[i0];
      re[i0] = ar + tr; im[i0] = ai + ti;
      re[i1] = ar - tr; im[i1] = ai - ti;
    }
    __syncthreads();
  }
  const float scale = 1.0f / ((float)D_ * (float)L_);
  for (int l = (int)threadIdx.x; l < L_; l += 256)
    mv[(size_t)b * L_ + l] = re[l] * scale;
}

// ------------------------------------------------------------------
// topk: 1024 threads, shuffle-reduce argmax x7, then softmax.
// ------------------------------------------------------------------
__global__ __launch_bounds__(1024) void topk_kernel(
    const float* __restrict__ mv, int* __restrict__ idx, float* __restrict__ wts)
{
  __shared__ float vals[L_];
  __shared__ float wm[16];
  __shared__ int wi[16];
  __shared__ int chosen[TOPK];
  const int t = (int)threadIdx.x;
  const int lane = t & 63, wv = t >> 6;
  float s0 = 0.f, s1 = 0.f;
#pragma unroll
  for (int b = 0; b < B_; ++b) {
    s0 += mv[(size_t)b * L_ + t];
    s1 += mv[(size_t)b * L_ + t + 1024];
  }
  vals[t] = s0; vals[t + 1024] = s1;
  __syncthreads();
  for (int kk = 0; kk < TOPK; ++kk) {
    float v0 = vals[t]; int i0 = t;
    const float v1 = vals[t + 1024];
    if (v1 > v0) { v0 = v1; i0 = t + 1024; }
#pragma unroll
    for (int off = 32; off; off >>= 1) {
      const float ov = __shfl_xor(v0, off, 64);
      const int oi = __shfl_xor(i0, off, 64);
      if (ov > v0 || (ov == v0 && oi < i0)) { v0 = ov; i0 = oi; }
    }
    if (lane == 0) { wm[wv] = v0; wi[wv] = i0; }
    __syncthreads();
    if (t == 0) {
      float m = wm[0]; int mi = wi[0];
      for (int i2 = 1; i2 < 16; ++i2)
        if (wm[i2] > m || (wm[i2] == m && wi[i2] < mi)) { m = wm[i2]; mi = wi[i2]; }
      chosen[kk] = mi; idx[kk] = mi; vals[mi] = -1e30f;
    }
    __syncthreads();
  }
  if (t < B_) {
    float w[TOPK];
    float mx = -1e30f;
#pragma unroll
    for (int kk = 0; kk < TOPK; ++kk) {
      w[kk] = mv[(size_t)t * L_ + chosen[kk]];
      mx = fmaxf(mx, w[kk]);
    }
    float sum = 0.f;
#pragma unroll
    for (int kk = 0; kk < TOPK; ++kk) { w[kk] = __expf(w[kk] - mx); sum += w[kk]; }
    const float inv = 1.0f / sum;
#pragma unroll
    for (int kk = 0; kk < TOPK; ++kk) wts[t * TOPK + kk] = w[kk] * inv;
  }
}

// ------------------------------------------------------------------
// context: f16 in, f16 out.
// ------------------------------------------------------------------
__global__ __launch_bounds__(128) void context_kernel(
    const _Float16* __restrict__ v, const int* __restrict__ idx,
    const float* __restrict__ wts, _Float16* __restrict__ ctx)
{
  const int bl = (int)blockIdx.x;
  const int b = bl >> LOG2L;
  const int l = bl & (L_ - 1);
  const int c = (int)threadIdx.x;
  float acc0 = 0.f, acc1 = 0.f, acc2 = 0.f, acc3 = 0.f;
#pragma unroll
  for (int kk = 0; kk < TOPK; ++kk) {
    const float w = wts[b * TOPK + kk];
    const int src = (l + idx[kk]) & (L_ - 1);
    const half4 x = *reinterpret_cast<const half4*>(v + ((size_t)(b << LOG2L) + src) * D_ + c * 4);
    acc0 = fmaf(w, (float)x[0], acc0);
    acc1 = fmaf(w, (float)x[1], acc1);
    acc2 = fmaf(w, (float)x[2], acc2);
    acc3 = fmaf(w, (float)x[3], acc3);
  }
  half4 o;
  o[0] = (_Float16)acc0; o[1] = (_Float16)acc1;
  o[2] = (_Float16)acc2; o[3] = (_Float16)acc3;
  *reinterpret_cast<half4*>(ctx + ((size_t)(b << LOG2L) + l) * D_ + c * 4) = o;
}

// ------------------------------------------------------------------
extern "C" void kernel_launch(void* const* d_in, const int* in_sizes, int n_in,
                              void* d_out, int out_size, void* d_ws, size_t ws_size,
                              hipStream_t stream)
{
  (void)in_sizes; (void)n_in; (void)out_size; (void)ws_size;
  const float* Q   = (const float*)d_in[0];
  const float* K   = (const float*)d_in[1];
  const float* V   = (const float*)d_in[2];
  const float* WQ  = (const float*)d_in[3];
  const float* WK  = (const float*)d_in[4];
  const float* WV  = (const float*)d_in[5];
  const float* Wfc = (const float*)d_in[6];
  float* out = (float*)d_out;

  char* ws = (char*)d_ws;
  const size_t sz_h   = (size_t)M_ * D_ * sizeof(_Float16);    // 16.78 MB
  const size_t sz_w16 = (size_t)D_ * D_ * sizeof(_Float16);    // 512 KB
  _Float16*  qT16  = (_Float16*)(ws);
  _Float16*  kT16  = (_Float16*)(ws + sz_h);
  _Float16*  vs16  = (_Float16*)(ws + 2 * sz_h);
  _Float16*  ctx16 = (_Float16*)(ws + 3 * sz_h);
  _Float16*  WQt   = (_Float16*)(ws + 4 * sz_h);
  _Float16*  WKt   = (_Float16*)(ws + 4 * sz_h + sz_w16);
  _Float16*  WVt   = (_Float16*)(ws + 4 * sz_h + 2 * sz_w16);
  _Float16*  Wfct  = (_Float16*)(ws + 4 * sz_h + 3 * sz_w16);
  float*     S     = (float*)(ws + 4 * sz_h + 4 * sz_w16);
  float*     mv    = (float*)((char*)S + (size_t)B_ * L_ * 2 * sizeof(float));
  int*       idx   = (int*)((char*)mv + (size_t)B_ * L_ * sizeof(float));
  float*     wts   = (float*)((char*)idx + 64);

  convw_kernel<<<256, 256, 0, stream>>>(WQ, WK, WV, Wfc, WQt, WKt, WVt, Wfct);

  gemm_f16_kernel<0, 3><<<512, 256, 0, stream>>>(Q, nullptr, WQt, nullptr, qT16);
  gemm_f16_kernel<0, 3><<<512, 256, 0, stream>>>(K, nullptr, WKt, nullptr, kT16);

  hipMemsetAsync(S, 0, (size_t)B_ * L_ * 2 * sizeof(float), stream);
  corr_fft_kernel<<<B_ * (D_ / DCHUNK), 256, 0, stream>>>(qT16, kT16, S);
  ifft_kernel<<<B_, 256, 0, stream>>>(S, mv);
  topk_kernel<<<1, 1024, 0, stream>>>(mv, idx, wts);

  gemm_f16_kernel<0, 2><<<512, 256, 0, stream>>>(V, nullptr, WVt, nullptr, vs16);
  context_kernel<<<B_ * L_, 128, 0, stream>>>(vs16, idx, wts, ctx16);
  gemm_f16_kernel<1, 0><<<512, 256, 0, stream>>>(nullptr, ctx16, Wfct, out, nullptr);
}

// Round 6
// 182.087 us; speedup vs baseline: 4.8926x; 1.0044x over previous
//
#include <hip/hip_runtime.h>
#include <math.h>

#define B_ 8
#define L_ 2048
#define D_ 512
#define LOG2L 11
#define TOPK 7
#define M_ (B_ * L_)     // 16384

typedef __attribute__((ext_vector_type(8))) _Float16 half8;
typedef __attribute__((ext_vector_type(4))) _Float16 half4;
typedef __attribute__((ext_vector_type(4))) float f32x4;

// ------------------------------------------------------------------
// convw: 4 weight mats fp32 [512][512] (k-major) -> f16 [n][k]. One
// launch; blockIdx>>6 selects the matrix.
// ------------------------------------------------------------------
__global__ __launch_bounds__(256) void convw_kernel(
    const float* __restrict__ W0, const float* __restrict__ W1,
    const float* __restrict__ W2, const float* __restrict__ W3,
    _Float16* __restrict__ T0, _Float16* __restrict__ T1,
    _Float16* __restrict__ T2, _Float16* __restrict__ T3)
{
  __shared__ float tile[64][65];
  const int t = (int)threadIdx.x;
  const int mat = (int)blockIdx.x >> 6;
  const int tb = (int)blockIdx.x & 63;
  const float* W = (mat == 0) ? W0 : (mat == 1) ? W1 : (mat == 2) ? W2 : W3;
  _Float16* Wt = (mat == 0) ? T0 : (mat == 1) ? T1 : (mat == 2) ? T2 : T3;
  const int k0 = (tb >> 3) * 64;
  const int n0 = (tb & 7) * 64;
#pragma unroll
  for (int i = 0; i < 4; ++i) {
    const int kl = (t >> 4) + i * 16;
    const float4 v = *reinterpret_cast<const float4*>(&W[(size_t)(k0 + kl) * D_ + n0 + (t & 15) * 4]);
    tile[kl][(t & 15) * 4 + 0] = v.x;
    tile[kl][(t & 15) * 4 + 1] = v.y;
    tile[kl][(t & 15) * 4 + 2] = v.z;
    tile[kl][(t & 15) * 4 + 3] = v.w;
  }
  __syncthreads();
  const int nl = t >> 2, q = t & 3;
  half8 h0, h1;
#pragma unroll
  for (int j = 0; j < 8; ++j) {
    h0[j] = (_Float16)tile[q * 16 + j][nl];
    h1[j] = (_Float16)tile[q * 16 + 8 + j][nl];
  }
  _Float16* dst = &Wt[(size_t)(n0 + nl) * D_ + k0 + q * 16];
  *reinterpret_cast<half8*>(dst) = h0;
  *reinterpret_cast<half8*>(dst + 8) = h1;
}

// ------------------------------------------------------------------
// MFMA f16 GEMM: C = A[M,512] @ W using Wt[n][k] f16. 128x128 tile,
// BK=32, 4 waves. OUTMODE: 0 = fp32 [M,512]; 2 = f16 [M,512];
// 3 = f16 transposed [512][M] (acc reg idx is m -> half4 direct store).
// ------------------------------------------------------------------
#define LDSTR 40

template <int INBF, int OUTMODE>
__global__ __launch_bounds__(256) void gemm_f16_kernel(
    const float* __restrict__ Af, const _Float16* __restrict__ Ah,
    const _Float16* __restrict__ Wt,
    float* __restrict__ Cf, _Float16* __restrict__ Ch)
{
  __shared__ __align__(16) char smem[128 * LDSTR * 2 * 2];   // 20480 B
  _Float16* sA = (_Float16*)smem;
  _Float16* sB = sA + 128 * LDSTR;

  const int tid = (int)threadIdx.x;
  const int lane = tid & 63, wave = tid >> 6;
  const int wr = (wave >> 1) << 6, wc = (wave & 1) << 6;
  const int m0 = ((int)blockIdx.x >> 2) << 7;
  const int n0 = ((int)blockIdx.x & 3) << 7;

  const int srow = tid >> 1;            // 0..127
  const int sc0 = (tid & 1) << 4;       // 0 / 16

  f32x4 acc[4][4];
  const f32x4 zero = {0.f, 0.f, 0.f, 0.f};
#pragma unroll
  for (int i = 0; i < 4; ++i)
#pragma unroll
    for (int j = 0; j < 4; ++j) acc[i][j] = zero;

  const int fr = lane & 15;
  const int g8 = (lane >> 4) << 3;

  for (int k0 = 0; k0 < D_; k0 += 32) {
    half8 ha0, ha1, hb0, hb1;
    if constexpr (INBF == 0) {
      const float* ap = Af + (size_t)(m0 + srow) * D_ + k0 + sc0;
      float tmp[16];
#pragma unroll
      for (int j = 0; j < 4; ++j) {
        const float4 v = *reinterpret_cast<const float4*>(ap + j * 4);
        tmp[j * 4 + 0] = v.x; tmp[j * 4 + 1] = v.y;
        tmp[j * 4 + 2] = v.z; tmp[j * 4 + 3] = v.w;
      }
#pragma unroll
      for (int j = 0; j < 8; ++j) { ha0[j] = (_Float16)tmp[j]; ha1[j] = (_Float16)tmp[8 + j]; }
    } else {
      const _Float16* ap = Ah + (size_t)(m0 + srow) * D_ + k0 + sc0;
      ha0 = *reinterpret_cast<const half8*>(ap);
      ha1 = *reinterpret_cast<const half8*>(ap + 8);
    }
    {
      const _Float16* bp = Wt + (size_t)(n0 + srow) * D_ + k0 + sc0;
      hb0 = *reinterpret_cast<const half8*>(bp);
      hb1 = *reinterpret_cast<const half8*>(bp + 8);
    }

    __syncthreads();
    *reinterpret_cast<half8*>(&sA[srow * LDSTR + sc0]) = ha0;
    *reinterpret_cast<half8*>(&sA[srow * LDSTR + sc0 + 8]) = ha1;
    *reinterpret_cast<half8*>(&sB[srow * LDSTR + sc0]) = hb0;
    *reinterpret_cast<half8*>(&sB[srow * LDSTR + sc0 + 8]) = hb1;
    __syncthreads();

    half8 afr[4], bfr[4];
#pragma unroll
    for (int i = 0; i < 4; ++i) {
      afr[i] = *reinterpret_cast<const half8*>(&sA[(wr + i * 16 + fr) * LDSTR + g8]);
      bfr[i] = *reinterpret_cast<const half8*>(&sB[(wc + i * 16 + fr) * LDSTR + g8]);
    }
#pragma unroll
    for (int mi = 0; mi < 4; ++mi)
#pragma unroll
      for (int ni = 0; ni < 4; ++ni)
        acc[mi][ni] = __builtin_amdgcn_mfma_f32_16x16x32_f16(afr[mi], bfr[ni], acc[mi][ni], 0, 0, 0);
  }

  const int orow = (lane >> 4) << 2;   // m sub-offset (reg idx r adds 0..3)
  const int ocol = lane & 15;          // n sub-offset
  if constexpr (OUTMODE == 0) {
#pragma unroll
    for (int mi = 0; mi < 4; ++mi)
#pragma unroll
      for (int ni = 0; ni < 4; ++ni)
#pragma unroll
        for (int r = 0; r < 4; ++r)
          Cf[(size_t)(m0 + wr + mi * 16 + orow + r) * D_ + n0 + wc + ni * 16 + ocol] = acc[mi][ni][r];
  } else if constexpr (OUTMODE == 2) {
#pragma unroll
    for (int mi = 0; mi < 4; ++mi)
#pragma unroll
      for (int ni = 0; ni < 4; ++ni)
#pragma unroll
        for (int r = 0; r < 4; ++r)
          Ch[(size_t)(m0 + wr + mi * 16 + orow + r) * D_ + n0 + wc + ni * 16 + ocol] = (_Float16)acc[mi][ni][r];
  } else {
    // CT[n][m] f16: acc[mi][ni] holds 4 consecutive m -> half4 store
#pragma unroll
    for (int ni = 0; ni < 4; ++ni) {
      const size_t nrow = (size_t)(n0 + wc + ni * 16 + ocol) * M_;
#pragma unroll
      for (int mi = 0; mi < 4; ++mi) {
        half4 hv;
        hv[0] = (_Float16)acc[mi][ni][0]; hv[1] = (_Float16)acc[mi][ni][1];
        hv[2] = (_Float16)acc[mi][ni][2]; hv[3] = (_Float16)acc[mi][ni][3];
        *reinterpret_cast<half4*>(&Ch[nrow + m0 + wr + mi * 16 + orow]) = hv;
      }
    }
  }
}

// ------------------------------------------------------------------
// corr_fft v3: 4-round register FFT (radix-8 per round via 3 fused
// radix-2 stages). Each thread holds 8 complex elems; 3 LDS exchanges
// + final write. DIF: natural in -> bit-reversed out. f16 input.
// ------------------------------------------------------------------
__device__ __forceinline__ int rev11(int x) {
  return (int)(__brev((unsigned)x) >> (32 - LOG2L));
}

#define DCHUNK 4
#define PADI(i) ((i) + ((i) >> 5))

#define BFLY(j0, j1, wr_, wi_) { \
  const float ar = xr[j0], ai = xi[j0], br = xr[j1], bi = xi[j1]; \
  xr[j0] = ar + br; xi[j0] = ai + bi; \
  const float tr = ar - br, ti = ai - bi; \
  xr[j1] = tr * (wr_) - ti * (wi_); \
  xi[j1] = tr * (wi_) + ti * (wr_); }

__global__ __launch_bounds__(256) void corr_fft_kernel(
    const _Float16* __restrict__ qT, const _Float16* __restrict__ kT,
    float* __restrict__ S)
{
  __shared__ float re[2112];
  __shared__ float im[2112];
  const int t = (int)threadIdx.x;
  const int blk = (int)blockIdx.x;
  const int b = blk >> 7;
  const int d0 = (blk & 127) * DCHUNK;
  const int u2 = t & 31, u3 = t & 3;

  // base twiddles: W_N^k = exp(-2*pi*i*k/N); derive halves by squaring
  float w2048r, w2048i, w256r, w256i, w32r, w32i;
  {
    float s_, c_;
    __sincosf(-6.283185307179586f * (float)t / 2048.f, &s_, &c_);
    w2048r = c_; w2048i = s_;
    __sincosf(-6.283185307179586f * (float)u2 / 256.f, &s_, &c_);
    w256r = c_; w256i = s_;
    __sincosf(-6.283185307179586f * (float)u3 / 32.f, &s_, &c_);
    w32r = c_; w32i = s_;
  }
  const float w1024r = w2048r * w2048r - w2048i * w2048i, w1024i = 2.f * w2048r * w2048i;
  const float w512r  = w1024r * w1024r - w1024i * w1024i, w512i  = 2.f * w1024r * w1024i;
  const float w128r  = w256r * w256r - w256i * w256i,     w128i  = 2.f * w256r * w256i;
  const float w64r   = w128r * w128r - w128i * w128i,     w64i   = 2.f * w128r * w128i;
  const float w16r   = w32r * w32r - w32i * w32i,         w16i   = 2.f * w32r * w32i;
  const float w8r    = w16r * w16r - w16i * w16i,         w8i    = 2.f * w16r * w16i;

  const float C_ = 0.70710678118654752f;
  const float W8R[4] = {1.f, C_, 0.f, -C_};
  const float W8I[4] = {0.f, -C_, -1.f, -C_};

  float pr[8] = {}, pi_[8] = {};

  for (int dc = 0; dc < DCHUNK; ++dc) {
    const int d = d0 + dc;
    const _Float16* qrow = qT + (size_t)d * M_ + (size_t)b * L_;
    const _Float16* krow = kT + (size_t)d * M_ + (size_t)b * L_;

    float xr[8], xi[8];
#pragma unroll
    for (int j = 0; j < 8; ++j) {
      xr[j] = (float)qrow[t + 256 * j];
      xi[j] = (float)krow[t + 256 * j];
    }

    // ---- round 1: stages half=1024,512,256 (elem j at pos t+256j)
#pragma unroll
    for (int j = 0; j < 4; ++j) {
      const float wr_ = w2048r * W8R[j] - w2048i * W8I[j];
      const float wi_ = w2048r * W8I[j] + w2048i * W8R[j];
      BFLY(j, j + 4, wr_, wi_);
    }
#pragma unroll
    for (int base = 0; base < 8; base += 4) {
      BFLY(base + 0, base + 2, w1024r, w1024i);
      BFLY(base + 1, base + 3, w1024i, -w1024r);   // * W_4^1 = -i
    }
#pragma unroll
    for (int a = 0; a < 8; a += 2) BFLY(a, a + 1, w512r, w512i);

    // ---- exchange 1: pos t+256j -> pos (t>>5)*256 + (t&31) + 32j
    __syncthreads();   // prior product reads done
#pragma unroll
    for (int j = 0; j < 8; ++j) {
      const int p = t + 256 * j;
      re[PADI(p)] = xr[j]; im[PADI(p)] = xi[j];
    }
    __syncthreads();
#pragma unroll
    for (int j = 0; j < 8; ++j) {
      const int p = ((t >> 5) << 8) + u2 + 32 * j;
      xr[j] = re[PADI(p)]; xi[j] = im[PADI(p)];
    }

    // ---- round 2: stages half=128,64,32
#pragma unroll
    for (int j = 0; j < 4; ++j) {
      const float wr_ = w256r * W8R[j] - w256i * W8I[j];
      const float wi_ = w256r * W8I[j] + w256i * W8R[j];
      BFLY(j, j + 4, wr_, wi_);
    }
#pragma unroll
    for (int base = 0; base < 8; base += 4) {
      BFLY(base + 0, base + 2, w128r, w128i);
      BFLY(base + 1, base + 3, w128i, -w128r);
    }
#pragma unroll
    for (int a = 0; a < 8; a += 2) BFLY(a, a + 1, w64r, w64i);

    // ---- exchange 2 -> pos (t>>2)*32 + (t&3) + 4j
    __syncthreads();
#pragma unroll
    for (int j = 0; j < 8; ++j) {
      const int p = ((t >> 5) << 8) + u2 + 32 * j;
      re[PADI(p)] = xr[j]; im[PADI(p)] = xi[j];
    }
    __syncthreads();
#pragma unroll
    for (int j = 0; j < 8; ++j) {
      const int p = ((t >> 2) << 5) + u3 + 4 * j;
      xr[j] = re[PADI(p)]; xi[j] = im[PADI(p)];
    }

    // ---- round 3: stages half=16,8,4
#pragma unroll
    for (int j = 0; j < 4; ++j) {
      const float wr_ = w32r * W8R[j] - w32i * W8I[j];
      const float wi_ = w32r * W8I[j] + w32i * W8R[j];
      BFLY(j, j + 4, wr_, wi_);
    }
#pragma unroll
    for (int base = 0; base < 8; base += 4) {
      BFLY(base + 0, base + 2, w16r, w16i);
      BFLY(base + 1, base + 3, w16i, -w16r);
    }
#pragma unroll
    for (int a = 0; a < 8; a += 2) BFLY(a, a + 1, w8r, w8i);

    // ---- exchange 3 -> pos 8t+j (contiguous)
    __syncthreads();
#pragma unroll
    for (int j = 0; j < 8; ++j) {
      const int p = ((t >> 2) << 5) + u3 + 4 * j;
      re[PADI(p)] = xr[j]; im[PADI(p)] = xi[j];
    }
    __syncthreads();
#pragma unroll
    for (int j = 0; j < 8; ++j) {
      const int p = 8 * t + j;
      xr[j] = re[PADI(p)]; xi[j] = im[PADI(p)];
    }

    // ---- round 4: stages half=2,1 (trivial twiddles)
#pragma unroll
    for (int base = 0; base < 8; base += 4) {
      BFLY(base + 0, base + 2, 1.f, 0.f);
      BFLY(base + 1, base + 3, 0.f, -1.f);
    }
#pragma unroll
    for (int a = 0; a < 8; a += 2) BFLY(a, a + 1, 1.f, 0.f);

    // ---- final write (in-place, thread-local positions)
#pragma unroll
    for (int j = 0; j < 8; ++j) {
      const int p = 8 * t + j;
      re[PADI(p)] = xr[j]; im[PADI(p)] = xi[j];
    }
    __syncthreads();

    // ---- Hermitian split + product (pos p holds freq rev11(p))
#pragma unroll
    for (int i = 0; i < 8; ++i) {
      const int p = t + 256 * i;
      const int f = rev11(p);
      const int fm = (L_ - f) & (L_ - 1);
      const int pm = rev11(fm);
      const float Ar = re[PADI(p)],  Ai = im[PADI(p)];
      const float Br = re[PADI(pm)], Bi = -im[PADI(pm)];
      const float Qr = 0.5f * (Ar + Br), Qi = 0.5f * (Ai + Bi);
      const float Cr = 0.5f * (Ai - Bi), Ci = 0.5f * (Ar - Br);
      pr[i]  += Qr * Cr - Qi * Ci;
      pi_[i] += Qr * Ci + Qi * Cr;
    }
  }

#pragma unroll
  for (int i = 0; i < 8; ++i) {
    const int p = t + 256 * i;
    atomicAdd(&S[((size_t)b * L_ + p) * 2 + 0], pr[i]);
    atomicAdd(&S[((size_t)b * L_ + p) * 2 + 1], pi_[i]);
  }
}

// ------------------------------------------------------------------
// Inverse DIT (bit-rev in, natural out), per b.
// ------------------------------------------------------------------
__global__ __launch_bounds__(256) void ifft_kernel(
    const float* __restrict__ S, float* __restrict__ mv)
{
  __shared__ float re[L_];
  __shared__ float im[L_];
  const int b = blockIdx.x;
  for (int p = (int)threadIdx.x; p < L_; p += 256) {
    re[p] = S[((size_t)b * L_ + p) * 2 + 0];
    im[p] = S[((size_t)b * L_ + p) * 2 + 1];
  }
  __syncthreads();
  for (int s = 1; s <= LOG2L; ++s) {
    const int half = 1 << (s - 1);
    for (int j = (int)threadIdx.x; j < (L_ >> 1); j += 256) {
      const int pos = j & (half - 1);
      const int i0 = ((j >> (s - 1)) << s) + pos;
      const int i1 = i0 + half;
      const float ang = 3.14159265358979323846f * (float)pos / (float)half;
      float wi, wr;
      __sincosf(ang, &wi, &wr);
      const float br = re[i1], bi = im[i1];
      const float tr = br * wr - bi * wi;
      const float ti = br * wi + bi * wr;
      const float ar = re[i0], ai = im[i0];
      re[i0] = ar + tr; im[i0] = ai + ti;
      re[i1] = ar - tr; im[i1] = ai - ti;
    }
    __syncthreads();
  }
  const float scale = 1.0f / ((float)D_ * (float)L_);
  for (int l = (int)threadIdx.x; l < L_; l += 256)
    mv[(size_t)b * L_ + l] = re[l] * scale;
}

// ------------------------------------------------------------------
// topk: 1024 threads, shuffle-reduce argmax x7, then softmax.
// ------------------------------------------------------------------
__global__ __launch_bounds__(1024) void topk_kernel(
    const float* __restrict__ mv, int* __restrict__ idx, float* __restrict__ wts)
{
  __shared__ float vals[L_];
  __shared__ float wm[16];
  __shared__ int wi[16];
  __shared__ int chosen[TOPK];
  const int t = (int)threadIdx.x;
  const int lane = t & 63, wv = t >> 6;
  float s0 = 0.f, s1 = 0.f;
#pragma unroll
  for (int b = 0; b < B_; ++b) {
    s0 += mv[(size_t)b * L_ + t];
    s1 += mv[(size_t)b * L_ + t + 1024];
  }
  vals[t] = s0; vals[t + 1024] = s1;
  __syncthreads();
  for (int kk = 0; kk < TOPK; ++kk) {
    float v0 = vals[t]; int i0 = t;
    const float v1 = vals[t + 1024];
    if (v1 > v0) { v0 = v1; i0 = t + 1024; }
#pragma unroll
    for (int off = 32; off; off >>= 1) {
      const float ov = __shfl_xor(v0, off, 64);
      const int oi = __shfl_xor(i0, off, 64);
      if (ov > v0 || (ov == v0 && oi < i0)) { v0 = ov; i0 = oi; }
    }
    if (lane == 0) { wm[wv] = v0; wi[wv] = i0; }
    __syncthreads();
    if (t == 0) {
      float m = wm[0]; int mi = wi[0];
      for (int i2 = 1; i2 < 16; ++i2)
        if (wm[i2] > m || (wm[i2] == m && wi[i2] < mi)) { m = wm[i2]; mi = wi[i2]; }
      chosen[kk] = mi; idx[kk] = mi; vals[mi] = -1e30f;
    }
    __syncthreads();
  }
  if (t < B_) {
    float w[TOPK];
    float mx = -1e30f;
#pragma unroll
    for (int kk = 0; kk < TOPK; ++kk) {
      w[kk] = mv[(size_t)t * L_ + chosen[kk]];
      mx = fmaxf(mx, w[kk]);
    }
    float sum = 0.f;
#pragma unroll
    for (int kk = 0; kk < TOPK; ++kk) { w[kk] = __expf(w[kk] - mx); sum += w[kk]; }
    const float inv = 1.0f / sum;
#pragma unroll
    for (int kk = 0; kk < TOPK; ++kk) wts[t * TOPK + kk] = w[kk] * inv;
  }
}

// ------------------------------------------------------------------
// context: f16 in, f16 out.
// ------------------------------------------------------------------
__global__ __launch_bounds__(128) void context_kernel(
    const _Float16* __restrict__ v, const int* __restrict__ idx,
    const float* __restrict__ wts, _Float16* __restrict__ ctx)
{
  const int bl = (int)blockIdx.x;
  const int b = bl >> LOG2L;
  const int l = bl & (L_ - 1);
  const int c = (int)threadIdx.x;
  float acc0 = 0.f, acc1 = 0.f, acc2 = 0.f, acc3 = 0.f;
#pragma unroll
  for (int kk = 0; kk < TOPK; ++kk) {
    const float w = wts[b * TOPK + kk];
    const int src = (l + idx[kk]) & (L_ - 1);
    const half4 x = *reinterpret_cast<const half4*>(v + ((size_t)(b << LOG2L) + src) * D_ + c * 4);
    acc0 = fmaf(w, (float)x[0], acc0);
    acc1 = fmaf(w, (float)x[1], acc1);
    acc2 = fmaf(w, (float)x[2], acc2);
    acc3 = fmaf(w, (float)x[3], acc3);
  }
  half4 o;
  o[0] = (_Float16)acc0; o[1] = (_Float16)acc1;
  o[2] = (_Float16)acc2; o[3] = (_Float16)acc3;
  *reinterpret_cast<half4*>(ctx + ((size_t)(b << LOG2L) + l) * D_ + c * 4) = o;
}

// ------------------------------------------------------------------
extern "C" void kernel_launch(void* const* d_in, const int* in_sizes, int n_in,
                              void* d_out, int out_size, void* d_ws, size_t ws_size,
                              hipStream_t stream)
{
  (void)in_sizes; (void)n_in; (void)out_size; (void)ws_size;
  const float* Q   = (const float*)d_in[0];
  const float* K   = (const float*)d_in[1];
  const float* V   = (const float*)d_in[2];
  const float* WQ  = (const float*)d_in[3];
  const float* WK  = (const float*)d_in[4];
  const float* WV  = (const float*)d_in[5];
  const float* Wfc = (const float*)d_in[6];
  float* out = (float*)d_out;

  char* ws = (char*)d_ws;
  const size_t sz_h   = (size_t)M_ * D_ * sizeof(_Float16);    // 16.78 MB
  const size_t sz_w16 = (size_t)D_ * D_ * sizeof(_Float16);    // 512 KB
  _Float16*  qT16  = (_Float16*)(ws);
  _Float16*  kT16  = (_Float16*)(ws + sz_h);
  _Float16*  vs16  = (_Float16*)(ws + 2 * sz_h);
  _Float16*  ctx16 = (_Float16*)(ws + 3 * sz_h);
  _Float16*  WQt   = (_Float16*)(ws + 4 * sz_h);
  _Float16*  WKt   = (_Float16*)(ws + 4 * sz_h + sz_w16);
  _Float16*  WVt   = (_Float16*)(ws + 4 * sz_h + 2 * sz_w16);
  _Float16*  Wfct  = (_Float16*)(ws + 4 * sz_h + 3 * sz_w16);
  float*     S     = (float*)(ws + 4 * sz_h + 4 * sz_w16);
  float*     mv    = (float*)((char*)S + (size_t)B_ * L_ * 2 * sizeof(float));
  int*       idx   = (int*)((char*)mv + (size_t)B_ * L_ * sizeof(float));
  float*     wts   = (float*)((char*)idx + 64);

  convw_kernel<<<256, 256, 0, stream>>>(WQ, WK, WV, Wfc, WQt, WKt, WVt, Wfct);

  gemm_f16_kernel<0, 3><<<512, 256, 0, stream>>>(Q, nullptr, WQt, nullptr, qT16);
  gemm_f16_kernel<0, 3><<<512, 256, 0, stream>>>(K, nullptr, WKt, nullptr, kT16);

  hipMemsetAsync(S, 0, (size_t)B_ * L_ * 2 * sizeof(float), stream);
  corr_fft_kernel<<<B_ * (D_ / DCHUNK), 256, 0, stream>>>(qT16, kT16, S);
  ifft_kernel<<<B_, 256, 0, stream>>>(S, mv);
  topk_kernel<<<1, 1024, 0, stream>>>(mv, idx, wts);

  gemm_f16_kernel<0, 2><<<512, 256, 0, stream>>>(V, nullptr, WVt, nullptr, vs16);
  context_kernel<<<B_ * L_, 128, 0, stream>>>(vs16, idx, wts, ctx16);
  gemm_f16_kernel<1, 0><<<512, 256, 0, stream>>>(nullptr, ctx16, Wfct, out, nullptr);
}